// Round 22
// baseline (678.294 us; speedup 1.0000x reference)
//
#include <hip/hip_runtime.h>
#include <hip/hip_bf16.h>
#include <cstdint>
#include <cstddef>

typedef __bf16 bf16x8 __attribute__((ext_vector_type(8)));
typedef float  f32x4  __attribute__((ext_vector_type(4)));
typedef __hip_bfloat16 hbf16;

#define DEVI static __device__ __forceinline__

DEVI unsigned short f2bf_bits(float x){
  hbf16 h = __float2bfloat16(x);
  return *reinterpret_cast<unsigned short*>(&h);
}
DEVI float gelu_tanh(float x){
  float u = x*(1.0f + 0.044715f*x*x);
  float t = exp2f(-2.3022119f*u);
  return x/(1.0f+t);
}

typedef __attribute__((address_space(1))) const unsigned int* gas_p;
typedef __attribute__((address_space(3))) unsigned int* las_p;
DEVI void gload16(const void* g, void* l){
  __builtin_amdgcn_global_load_lds((gas_p)g, (las_p)l, 16, 0, 0);
}

// ---------------- mod-vector GEMV (silu fused), dual-problem ----------------
__global__ __launch_bounds__(256) void mod_part_k(const float* __restrict__ vec_,
                                                  const float* __restrict__ W1,
                                                  const float* __restrict__ W2,
                                                  float* __restrict__ part){
  const float* W = blockIdx.z ? W2 : W1;
  float* po = part + (size_t)blockIdx.z*32*12288;
  int j  = blockIdx.x*1024 + threadIdx.x*4;
  int i0 = blockIdx.y*64;
  float4 acc = {0.f,0.f,0.f,0.f};
  for (int i=0;i<64;i++){
    float x = vec_[i0+i];
    float s = x/(1.0f+__expf(-x));        // silu fused
    float4 w = *(const float4*)(W + (size_t)(i0+i)*12288 + j);
    acc.x += s*w.x; acc.y += s*w.y; acc.z += s*w.z; acc.w += s*w.w;
  }
  *(float4*)(po + (size_t)blockIdx.y*12288 + j) = acc;
}

__global__ __launch_bounds__(256) void mod_red_k(const float* __restrict__ part,
                                                 const float* __restrict__ b1,
                                                 const float* __restrict__ b2,
                                                 float* __restrict__ out1,
                                                 float* __restrict__ out2){
  const float* p0 = part + (size_t)blockIdx.y*32*12288;
  const float* b  = blockIdx.y ? b2 : b1;
  float* out      = blockIdx.y ? out2 : out1;
  int j = blockIdx.x*1024 + threadIdx.x*4;
  float4 acc = *(const float4*)(b + j);
  #pragma unroll
  for (int y=0;y<32;y++){
    float4 p = *(const float4*)(p0 + (size_t)y*12288 + j);
    acc.x += p.x; acc.y += p.y; acc.z += p.z; acc.w += p.w;
  }
  *(float4*)(out + j) = acc;
}

// LayerNorm (no affine) + modulate -> bf16. Fused img + txt.
__global__ __launch_bounds__(256) void ln_mod_k(
    const float* __restrict__ Xi, const float* __restrict__ Xt,
    const float* __restrict__ sh_i, const float* __restrict__ sc_i,
    const float* __restrict__ sh_t, const float* __restrict__ sc_t,
    hbf16* __restrict__ Yi, hbf16* __restrict__ Yt){
  __shared__ float red[8];
  const int row = blockIdx.x, tid = threadIdx.x;
  const float* X; const float* sh; const float* sc; hbf16* Y; int r;
  if (row < 2048){ X = Xi; sh = sh_i; sc = sc_i; Y = Yi; r = row; }
  else           { X = Xt; sh = sh_t; sc = sc_t; Y = Yt; r = row - 2048; }
  const float* x = X + (size_t)r*2048;
  float4 a = *(const float4*)(x + tid*8);
  float4 c = *(const float4*)(x + tid*8 + 4);
  float s  = a.x+a.y+a.z+a.w + c.x+c.y+c.z+c.w;
  float s2 = a.x*a.x+a.y*a.y+a.z*a.z+a.w*a.w + c.x*c.x+c.y*c.y+c.z*c.z+c.w*c.w;
  #pragma unroll
  for (int m=1;m<64;m<<=1){ s += __shfl_xor(s,m,64); s2 += __shfl_xor(s2,m,64); }
  if ((tid&63)==0){ red[tid>>6] = s; red[4+(tid>>6)] = s2; }
  __syncthreads();
  float S  = red[0]+red[1]+red[2]+red[3];
  float S2 = red[4]+red[5]+red[6]+red[7];
  float mean = S*(1.f/2048.f);
  float var  = S2*(1.f/2048.f) - mean*mean;
  float rs = rsqrtf(var + 1e-6f);
  float xv[8] = {a.x,a.y,a.z,a.w,c.x,c.y,c.z,c.w};
  #pragma unroll
  for (int j=0;j<8;j++){
    int n = tid*8 + j;
    float yv = (xv[j]-mean)*rs*(1.f+sc[n]) + sh[n];
    Y[(size_t)r*2048 + n] = __float2bfloat16(yv);
  }
}

// transpose + fp32->bf16, fused img/txt pair: W [K][N] -> Wt [N][K].
__global__ __launch_bounds__(256) void transp3_k(const float* __restrict__ W1,
                                                 hbf16* __restrict__ Wt1,
                                                 const float* __restrict__ W2,
                                                 hbf16* __restrict__ Wt2,
                                                 int K, int N){
  const float* W = blockIdx.z ? W2 : W1;
  hbf16* Wt = blockIdx.z ? Wt2 : Wt1;
  __shared__ float tile[128][68];
  const int n0 = blockIdx.x*64, k0 = blockIdx.y*128;
  const int tid = threadIdx.x;
  #pragma unroll
  for (int i=0;i<8;i++){
    int c = i*256 + tid;
    int k = c>>4, nq = c&15;
    float4 v = *(const float4*)(W + (size_t)(k0+k)*N + n0 + nq*4);
    *(float4*)&tile[k][nq*4] = v;
  }
  __syncthreads();
  const int n = tid>>2, kseg = tid&3;
  unsigned short buf[32];
  #pragma unroll
  for (int j=0;j<32;j++) buf[j] = f2bf_bits(tile[kseg*32+j][n]);
  hbf16* dst = Wt + (size_t)(n0+n)*K + k0 + kseg*32;
  *(uint4*)(dst)      = *(const uint4*)&buf[0];
  *(uint4*)(dst + 8)  = *(const uint4*)&buf[8];
  *(uint4*)(dst + 16) = *(const uint4*)&buf[16];
  *(uint4*)(dst + 24) = *(const uint4*)&buf[24];
}

// bf16 transpose: V [2304][2048] -> Vt [2048][2304]
__global__ __launch_bounds__(256) void vtransp_k(const hbf16* __restrict__ V,
                                                 hbf16* __restrict__ Vt){
  __shared__ unsigned short tile[64][72];
  const int t0 = blockIdx.x*64, d0 = blockIdx.y*64;
  const int tid = threadIdx.x;
  #pragma unroll
  for (int i=0;i<2;i++){
    int c = i*256 + tid, row = c>>3, jj = c&7;
    uint4 v = *(const uint4*)(V + (size_t)(t0+row)*2048 + d0 + jj*8);
    *(uint4*)&tile[row][jj*8] = v;
  }
  __syncthreads();
  const int d = tid>>2, seg = tid&3;
  unsigned short buf[16];
  #pragma unroll
  for (int j=0;j<16;j++) buf[j] = tile[seg*16+j][d];
  *(uint4*)(Vt + (size_t)(d0+d)*2304 + t0 + seg*16)     = *(const uint4*)&buf[0];
  *(uint4*)(Vt + (size_t)(d0+d)*2304 + t0 + seg*16 + 8) = *(const uint4*)&buf[8];
}

// ---------------- GEMM 128^2, BK=128, dual-problem (proj / fc2) ----------------
// A/B this round: XCD chunk swizzle REMOVED (w2 = w) — L3-resident working set.
template<int EPI>
__global__ __launch_bounds__(256,2) void gemmbk_k(
    const hbf16* __restrict__ A1, const hbf16* __restrict__ B1,
    float* __restrict__ Cf1, const float* __restrict__ bias1,
    const float* __restrict__ gate1, const float* __restrict__ res1,
    const hbf16* __restrict__ A2, const hbf16* __restrict__ B2,
    float* __restrict__ Cf2, const float* __restrict__ bias2,
    const float* __restrict__ gate2, const float* __restrict__ res2,
    int nbx, int nby1, int nby2, int N, int K)
{
  __shared__ unsigned short As[128*128];   // 32 KB
  __shared__ unsigned short Bs[128*128];   // 32 KB
  const int tid = threadIdx.x;
  const int wv = tid>>6, ln = tid&63;
  const int w2 = blockIdx.x;               // no XCD swizzle (L3-fit A/B)
  int n0, m0;
  const hbf16* A; const hbf16* Bt; float* Cf;
  const float* bias; const float* gate; const float* res;
  if (w2 < nbx*nby1){
    n0 = (w2/nby1)*128; m0 = (w2%nby1)*128;
    A=A1; Bt=B1; Cf=Cf1; bias=bias1; gate=gate1; res=res1;
  } else {
    int w3 = w2 - nbx*nby1;
    n0 = (w3/nby2)*128; m0 = (w3%nby2)*128;
    A=A2; Bt=B2; Cf=Cf2; bias=bias2; gate=gate2; res=res2;
  }
  const int wm = (wv>>1)*64, wn = (wv&1)*64;
  const int lm = ln&15, lk = ln>>4;
  f32x4 acc[4][4];
  #pragma unroll
  for (int i=0;i<4;i++)
    #pragma unroll
    for (int j=0;j<4;j++) acc[i][j] = (f32x4){0.f,0.f,0.f,0.f};

  const int srow = tid>>4;                  // 0..15 (row mod 16)
  const int jsrc = (tid&15) ^ srow;         // involution partner of read swizzle
  const int NT = K>>7;

  for (int kt=0; kt<NT; ++kt){
    const int kk = kt<<7;
    #pragma unroll
    for (int i=0;i<8;i++){
      int row = i*16 + srow;
      gload16(A  + (size_t)(m0+row)*K + kk + jsrc*8, &As[(i*256+tid)*8]);
      gload16(Bt + (size_t)(n0+row)*K + kk + jsrc*8, &Bs[(i*256+tid)*8]);
    }
    __syncthreads();
    #pragma unroll
    for (int ks=0; ks<4; ++ks){
      bf16x8 af[4], bfv[4];
      #pragma unroll
      for (int qq=0;qq<4;qq++){
        int row = wm + qq*16 + lm;
        int jj  = ks*4 + lk;
        af[qq] = *(const bf16x8*)&As[row*128 + ((jj^(row&15))<<3)];
      }
      #pragma unroll
      for (int qq=0;qq<4;qq++){
        int row = wn + qq*16 + lm;
        int jj  = ks*4 + lk;
        bfv[qq] = *(const bf16x8*)&Bs[row*128 + ((jj^(row&15))<<3)];
      }
      #pragma unroll
      for (int i=0;i<4;i++)
        #pragma unroll
        for (int j=0;j<4;j++)
          acc[i][j] = __builtin_amdgcn_mfma_f32_16x16x32_bf16(af[i], bfv[j], acc[i][j], 0,0,0);
    }
    __syncthreads();
  }
  #pragma unroll
  for (int i=0;i<4;i++){
    int mbase = m0 + wm + i*16 + lk*4;
    #pragma unroll
    for (int j=0;j<4;j++){
      int n = n0 + wn + j*16 + lm;
      #pragma unroll
      for (int r=0;r<4;r++){
        size_t idx = (size_t)(mbase+r)*N + n;
        float v = acc[i][j][r];
        if constexpr (EPI==2){ Cf[idx] = res[idx] + gate[n]*v; }
        else { Cf[idx] = res[idx] + gate[n]*(v + bias[n]); }
      }
    }
  }
}

// ---------------- GEMM 256Mx128N, 8 waves, per-wave 64x64 (fc1) ----------------
template<int EPI>
__global__ __launch_bounds__(512) void gemm256n_k(
    const hbf16* __restrict__ A1, const hbf16* __restrict__ B1,
    hbf16* __restrict__ Cb1, const float* __restrict__ bias1,
    const hbf16* __restrict__ A2, const hbf16* __restrict__ B2,
    hbf16* __restrict__ Cb2, const float* __restrict__ bias2,
    int nbx, int nby1, int nby2, int N, int K)
{
  __shared__ unsigned short As[256*64];   // 32 KB
  __shared__ unsigned short Bs[128*64];   // 16 KB
  const int tid = threadIdx.x;
  const int wv = tid>>6, ln = tid&63;
  const int w2 = blockIdx.x;               // no XCD swizzle (L3-fit A/B)
  int n0, m0;
  const hbf16* A; const hbf16* Bt; hbf16* Cb; const float* bias;
  if (w2 < nbx*nby1){
    n0 = (w2/nby1)*128; m0 = (w2%nby1)*256;
    A=A1; Bt=B1; Cb=Cb1; bias=bias1;
  } else {
    int w3 = w2 - nbx*nby1;
    n0 = (w3/nby2)*128; m0 = (w3%nby2)*256;
    A=A2; Bt=B2; Cb=Cb2; bias=bias2;
  }
  const int wm = wv>>1, wn = wv&1;       // 4M x 2N waves
  const int lm = ln&15, lk = ln>>4;
  f32x4 acc[4][4];
  #pragma unroll
  for (int i=0;i<4;i++)
    #pragma unroll
    for (int j=0;j<4;j++) acc[i][j] = (f32x4){0.f,0.f,0.f,0.f};

  const int srow = tid>>3;               // 0..63
  const int jsrc = (tid&7) ^ (srow&7);
  const int NT = K>>6;

  for (int kt=0; kt<NT; ++kt){
    const int kk = kt<<6;
    #pragma unroll
    for (int i=0;i<4;i++)
      gload16(A + (size_t)(m0 + i*64 + srow)*K + kk + jsrc*8, &As[(i*512+tid)*8]);
    #pragma unroll
    for (int i=0;i<2;i++)
      gload16(Bt + (size_t)(n0 + i*64 + srow)*K + kk + jsrc*8, &Bs[(i*512+tid)*8]);
    __syncthreads();
    #pragma unroll
    for (int ks=0; ks<2; ++ks){
      bf16x8 af[4], bfv[4];
      #pragma unroll
      for (int qq=0;qq<4;qq++){
        int row = wm*64 + qq*16 + lm;
        int jj  = ks*4 + lk;
        af[qq] = *(const bf16x8*)&As[row*64 + ((jj^(row&7))<<3)];
      }
      #pragma unroll
      for (int qq=0;qq<4;qq++){
        int row = wn*64 + qq*16 + lm;
        int jj  = ks*4 + lk;
        bfv[qq] = *(const bf16x8*)&Bs[row*64 + ((jj^(row&7))<<3)];
      }
      #pragma unroll
      for (int i=0;i<4;i++)
        #pragma unroll
        for (int j=0;j<4;j++)
          acc[i][j] = __builtin_amdgcn_mfma_f32_16x16x32_bf16(af[i], bfv[j], acc[i][j], 0,0,0);
    }
    __syncthreads();
  }
  #pragma unroll
  for (int i=0;i<4;i++){
    int mbase = m0 + wm*64 + i*16 + lk*4;
    #pragma unroll
    for (int j=0;j<4;j++){
      int n = n0 + wn*64 + j*16 + lm;
      #pragma unroll
      for (int r=0;r<4;r++){
        size_t idx = (size_t)(mbase+r)*N + n;
        float v = acc[i][j][r];
        if constexpr (EPI==1){ Cb[idx] = __float2bfloat16(gelu_tanh(v + bias[n])); }
        else { Cb[idx] = __float2bfloat16(v); }
      }
    }
  }
}

// ---------------- qkv GEMM 256Mx128N with fused RMSNorm + RoPE epilogue ----------------
__global__ __launch_bounds__(512) void gemmqkv_k(
    const hbf16* __restrict__ A1, const hbf16* __restrict__ B1,
    const float* __restrict__ qn1, const float* __restrict__ kn1,
    int tok1, int rope1,
    const hbf16* __restrict__ A2, const hbf16* __restrict__ B2,
    const float* __restrict__ qn2, const float* __restrict__ kn2,
    int tok2, int rope2,
    const float* __restrict__ fcos_, const float* __restrict__ fsin_,
    hbf16* __restrict__ qb, hbf16* __restrict__ kb, hbf16* __restrict__ vb,
    int nbx, int nby1, int nby2, int K)
{
  __shared__ unsigned short As[256*64];
  __shared__ unsigned short Bs[128*64];
  __shared__ float ssb[2][256];
  const int tid = threadIdx.x;
  const int wv = tid>>6, ln = tid&63;
  const int w2 = blockIdx.x;               // no XCD swizzle (L3-fit A/B)
  int n0, m0, tok, dorope;
  const hbf16* A; const hbf16* Bt; const float* qn; const float* kn;
  if (w2 < nbx*nby1){
    n0 = (w2/nby1)*128; m0 = (w2%nby1)*256;
    A=A1; Bt=B1; qn=qn1; kn=kn1; tok=tok1; dorope=rope1;
  } else {
    int w3 = w2 - nbx*nby1;
    n0 = (w3/nby2)*128; m0 = (w3%nby2)*256;
    A=A2; Bt=B2; qn=qn2; kn=kn2; tok=tok2; dorope=rope2;
  }
  const int wm = wv>>1, wn = wv&1;
  const int lm = ln&15, lk = ln>>4;
  f32x4 acc[4][4];
  #pragma unroll
  for (int i=0;i<4;i++)
    #pragma unroll
    for (int j=0;j<4;j++) acc[i][j] = (f32x4){0.f,0.f,0.f,0.f};

  const int srow = tid>>3;
  const int jsrc = (tid&7) ^ (srow&7);
  const int NT = K>>6;

  for (int kt=0; kt<NT; ++kt){
    const int kk = kt<<6;
    #pragma unroll
    for (int i=0;i<4;i++)
      gload16(A + (size_t)(m0 + i*64 + srow)*K + kk + jsrc*8, &As[(i*512+tid)*8]);
    #pragma unroll
    for (int i=0;i<2;i++)
      gload16(Bt + (size_t)(n0 + i*64 + srow)*K + kk + jsrc*8, &Bs[(i*512+tid)*8]);
    __syncthreads();
    #pragma unroll
    for (int ks=0; ks<2; ++ks){
      bf16x8 af[4], bfv[4];
      #pragma unroll
      for (int qq=0;qq<4;qq++){
        int row = wm*64 + qq*16 + lm;
        int jj  = ks*4 + lk;
        af[qq] = *(const bf16x8*)&As[row*64 + ((jj^(row&7))<<3)];
      }
      #pragma unroll
      for (int qq=0;qq<4;qq++){
        int row = wn*64 + qq*16 + lm;
        int jj  = ks*4 + lk;
        bfv[qq] = *(const bf16x8*)&Bs[row*64 + ((jj^(row&7))<<3)];
      }
      #pragma unroll
      for (int i=0;i<4;i++)
        #pragma unroll
        for (int j=0;j<4;j++)
          acc[i][j] = __builtin_amdgcn_mfma_f32_16x16x32_bf16(af[i], bfv[j], acc[i][j], 0,0,0);
    }
    __syncthreads();
  }

  const int which = n0 >> 11;        // 0:q 1:k 2:v
  const int head  = (n0 >> 7) & 15;
  if (which == 2){
    #pragma unroll
    for (int i=0;i<4;i++){
      int mbase = m0 + wm*64 + i*16 + lk*4;
      #pragma unroll
      for (int j=0;j<4;j++){
        int d = wn*64 + j*16 + lm;
        #pragma unroll
        for (int r=0;r<4;r++)
          vb[(size_t)(tok + mbase + r)*2048 + head*128 + d] = __float2bfloat16(acc[i][j][r]);
      }
    }
  } else {
    #pragma unroll
    for (int i=0;i<4;i++){
      #pragma unroll
      for (int r=0;r<4;r++){
        float p = 0.f;
        #pragma unroll
        for (int j=0;j<4;j++) p += acc[i][j][r]*acc[i][j][r];
        #pragma unroll
        for (int msk=1; msk<16; msk<<=1) p += __shfl_xor(p, msk, 64);
        if (lm == 0) ssb[wn][wm*64 + i*16 + lk*4 + r] = p;
      }
    }
    __syncthreads();
    const float* wgt = (which==0) ? qn : kn;
    const float qs = (which==0) ? 0.12751745f : 1.0f;   // 1/sqrt(128)*log2e for q
    hbf16* outb = (which==0) ? qb : kb;
    #pragma unroll
    for (int i=0;i<4;i++){
      #pragma unroll
      for (int r=0;r<4;r++){
        int row = wm*64 + i*16 + lk*4 + r;
        float ss = ssb[0][row] + ssb[1][row];
        float rs = rsqrtf(ss*(1.f/128.f) + 1e-6f) * qs;
        int t = m0 + row;
        #pragma unroll
        for (int j=0;j<4;j++){
          int d = wn*64 + j*16 + lm;
          float z = acc[i][j][r]*rs*wgt[d];
          float zp = __shfl_xor(z, 1, 64);
          float out;
          if (dorope){
            float c = fcos_[(size_t)t*128 + d];
            float s = fsin_[(size_t)t*128 + d];
            out = ((d&1)==0) ? (z*c - zp*s) : (z*c + zp*s);
          } else out = z;
          outb[(size_t)(tok + t)*2048 + head*128 + d] = __float2bfloat16(out);
        }
      }
    }
  }
}

// ---------------- flash attention: KV-split 4-way, bf16 partials ----------------
__global__ __launch_bounds__(512,4) void attn_k(
    const hbf16* __restrict__ Qg, const hbf16* __restrict__ Kg,
    const hbf16* __restrict__ Vtg, hbf16* __restrict__ sop01,
    hbf16* __restrict__ sop23, float* __restrict__ mlp)
{
  const int w = blockIdx.x;
  const int h = w & 15, quarter = (w>>4)&3, q0 = (w>>6)*128;
  const int tid = threadIdx.x, wv = tid>>6, ln = tid&63;
  __shared__ unsigned short Ks[2][64*128];
  __shared__ unsigned short Vs[2][128*64];
  __shared__ unsigned short Ps[8][16*64];

  bf16x8 qf[4];
  {
    const hbf16* qrow = Qg + (size_t)(q0 + wv*16 + (ln&15))*2048 + h*128 + (ln>>4)*8;
    #pragma unroll
    for (int ks=0;ks<4;ks++) qf[ks] = *(const bf16x8*)(qrow + ks*32);
  }

  f32x4 so[8];
  #pragma unroll
  for (int i=0;i<8;i++) so[i] = (f32x4){0.f,0.f,0.f,0.f};
  float m_run[4] = {-3e38f,-3e38f,-3e38f,-3e38f};
  float l_run[4] = {0.f,0.f,0.f,0.f};

  auto stage = [&](int buf, int kt){
    const int k0 = kt*64;
    #pragma unroll
    for (int i=0;i<2;i++){
      int c = i*512 + tid;
      int row = c>>4, jj = c&15;
      int js = jj ^ (row&7);
      gload16(Kg + (size_t)(k0+row)*2048 + h*128 + js*8, &Ks[buf][(i*512 + wv*64)*8]);
    }
    #pragma unroll
    for (int i=0;i<2;i++){
      int c = i*512 + tid;
      int row = c>>3, jj = c&7;
      int js = jj ^ (row&7);
      gload16(Vtg + (size_t)(h*128+row)*2304 + k0 + js*8, &Vs[buf][(i*512 + wv*64)*8]);
    }
  };

  const int t0 = quarter*9;
  stage(0, t0);
  __syncthreads();

  for (int it=0; it<9; ++it){
    const int cur = it&1;
    if (it+1 < 9) stage(cur^1, t0+it+1);

    f32x4 s[4];
    #pragma unroll
    for (int nb=0;nb<4;nb++) s[nb] = (f32x4){0.f,0.f,0.f,0.f};
    __builtin_amdgcn_s_setprio(1);
    #pragma unroll
    for (int ks=0;ks<4;ks++){
      #pragma unroll
      for (int nb=0;nb<4;nb++){
        int rk = nb*16 + (ln&15);
        int jq = ks*4 + (ln>>4);
        bf16x8 bk = *(const bf16x8*)&Ks[cur][rk*128 + ((jq^(rk&7))<<3)];
        s[nb] = __builtin_amdgcn_mfma_f32_16x16x32_bf16(qf[ks], bk, s[nb], 0,0,0);
      }
    }
    __builtin_amdgcn_s_setprio(0);

    float scl[4];
    #pragma unroll
    for (int r=0;r<4;r++){
      float m1 = fmaxf(fmaxf(s[0][r], s[1][r]), fmaxf(s[2][r], s[3][r]));
      #pragma unroll
      for (int msk=1; msk<16; msk<<=1) m1 = fmaxf(m1, __shfl_xor(m1, msk, 64));
      float mn = fmaxf(m_run[r], m1);
      scl[r] = exp2f(m_run[r] - mn);
      m_run[r] = mn;
    }
    #pragma unroll
    for (int nb=0;nb<4;nb++)
      #pragma unroll
      for (int r=0;r<4;r++)
        s[nb][r] = exp2f(s[nb][r] - m_run[r]);
    #pragma unroll
    for (int r=0;r<4;r++){
      float sm = s[0][r]+s[1][r]+s[2][r]+s[3][r];
      #pragma unroll
      for (int msk=1; msk<16; msk<<=1) sm += __shfl_xor(sm, msk, 64);
      l_run[r] = l_run[r]*scl[r] + sm;
    }
    #pragma unroll
    for (int nb2=0;nb2<8;nb2++)
      #pragma unroll
      for (int r=0;r<4;r++) so[nb2][r] *= scl[r];

    #pragma unroll
    for (int nb=0;nb<4;nb++)
      #pragma unroll
      for (int r=0;r<4;r++){
        int m = ((ln>>4)<<2) + r;
        int n = nb*16 + (ln&15);
        Ps[wv][m*64 + (((n>>3)^(m&7))<<3) + (n&7)] = f2bf_bits(s[nb][r]);
      }

    __builtin_amdgcn_s_setprio(1);
    #pragma unroll
    for (int ks=0;ks<2;ks++){
      int mrow = ln&15;
      bf16x8 pa = *(const bf16x8*)&Ps[wv][mrow*64 + (((ks*4+(ln>>4))^(mrow&7))<<3)];
      #pragma unroll
      for (int nb2=0;nb2<8;nb2++){
        int rv = nb2*16 + (ln&15);
        int jv = ks*4 + (ln>>4);
        bf16x8 bv = *(const bf16x8*)&Vs[cur][rv*64 + ((jv^(rv&7))<<3)];
        so[nb2] = __builtin_amdgcn_mfma_f32_16x16x32_bf16(pa, bv, so[nb2], 0,0,0);
      }
    }
    __builtin_amdgcn_s_setprio(0);
    __syncthreads();
  }

  hbf16* sbase = (quarter < 2 ? sop01 + (size_t)quarter*2304*2048
                              : sop23 + (size_t)(quarter-2)*2304*2048);
  #pragma unroll
  for (int r=0;r<4;r++){
    int m = q0 + wv*16 + ((ln>>4)<<2) + r;
    #pragma unroll
    for (int nb2=0;nb2<8;nb2++){
      int d = h*128 + nb2*16 + (ln&15);
      sbase[(size_t)m*2048 + d] = __float2bfloat16(so[nb2][r]);
    }
  }
  if ((ln&15)==0){
    #pragma unroll
    for (int r=0;r<4;r++){
      int m = q0 + wv*16 + ((ln>>4)<<2) + r;
      float* p = mlp + ((size_t)(quarter*2304 + m)*16 + h)*2;
      p[0] = m_run[r]; p[1] = l_run[r];
    }
  }
}

// merge the 4 KV quarters (bf16 partials)
__global__ __launch_bounds__(256) void amerge_k(const hbf16* __restrict__ sop01,
                                                const hbf16* __restrict__ sop23,
                                                const float* __restrict__ mlp,
                                                hbf16* __restrict__ Og){
  const int q = blockIdx.x, tid = threadIdx.x;
  const int d0 = tid*8, h = tid>>4;
  float mv[4], lv[4];
  float m = -3e38f;
  #pragma unroll
  for (int h4=0;h4<4;h4++){
    const float* p = mlp + ((size_t)(h4*2304 + q)*16 + h)*2;
    mv[h4] = p[0]; lv[h4] = p[1];
    m = fmaxf(m, mv[h4]);
  }
  float wgt[4], den = 0.f;
  #pragma unroll
  for (int h4=0;h4<4;h4++){ wgt[h4] = exp2f(mv[h4]-m); den += wgt[h4]*lv[h4]; }
  float inv = 1.0f/den;
  float acc[8] = {0,0,0,0,0,0,0,0};
  #pragma unroll
  for (int h4=0;h4<4;h4++){
    const hbf16* s = (h4<2 ? sop01 + (size_t)h4*2304*2048
                           : sop23 + (size_t)(h4-2)*2304*2048) + (size_t)q*2048 + d0;
    bf16x8 v = *(const bf16x8*)s;
    #pragma unroll
    for (int j=0;j<8;j++) acc[j] += wgt[h4]*(float)v[j];
  }
  hbf16* o = Og + (size_t)q*2048 + d0;
  #pragma unroll
  for (int j=0;j<8;j++) o[j] = __float2bfloat16(acc[j]*inv);
}

// ---------------- launcher ----------------

extern "C" void kernel_launch(void* const* d_in, const int* in_sizes, int n_in,
                              void* d_out, int out_size, void* d_ws, size_t ws_size,
                              hipStream_t stream) {
  (void)in_sizes; (void)n_in; (void)out_size; (void)ws_size;
  const float* img   = (const float*)d_in[0];
  const float* txt   = (const float*)d_in[1];
  const float* vec   = (const float*)d_in[2];
  const float* fcos  = (const float*)d_in[3];
  const float* fsin  = (const float*)d_in[4];
  const float* img_mod_w = (const float*)d_in[6];
  const float* img_mod_b = (const float*)d_in[7];
  const float* img_qkv_w = (const float*)d_in[8];
  const float* img_qn_w  = (const float*)d_in[9];
  const float* img_kn_w  = (const float*)d_in[10];
  const float* img_proj_w= (const float*)d_in[11];
  const float* img_fc1_w = (const float*)d_in[12];
  const float* img_fc1_b = (const float*)d_in[13];
  const float* img_fc2_w = (const float*)d_in[14];
  const float* img_fc2_b = (const float*)d_in[15];
  const float* txt_mod_w = (const float*)d_in[16];
  const float* txt_mod_b = (const float*)d_in[17];
  const float* txt_qkv_w = (const float*)d_in[18];
  const float* txt_qn_w  = (const float*)d_in[19];
  const float* txt_kn_w  = (const float*)d_in[20];
  const float* txt_proj_w= (const float*)d_in[21];
  const float* txt_fc1_w = (const float*)d_in[22];
  const float* txt_fc1_b = (const float*)d_in[23];
  const float* txt_fc2_w = (const float*)d_in[24];
  const float* txt_fc2_b = (const float*)d_in[25];

  float* out_img = (float*)d_out;
  float* out_txt = out_img + (size_t)2048*2048;

  char* ws = (char*)d_ws;
  size_t off = 0;
  auto alloc = [&](size_t bytes)->void*{
    void* p = ws + off; off += (bytes + 255) & ~(size_t)255; return p;
  };
  hbf16* wt1     = (hbf16*)alloc((size_t)16777216*2);
  hbf16* wt2     = (hbf16*)alloc((size_t)16777216*2);
  float* im      = (float*)alloc(12288*4);
  float* tm      = (float*)alloc(12288*4);
  float* part    = (float*)alloc((size_t)2*32*12288*4);
  // ix..tqkvb contiguous region later reused as sop01 (bf16 partials).
  hbf16* ix      = (hbf16*)alloc((size_t)2048*2048*2);
  hbf16* tx      = (hbf16*)alloc((size_t)256*2048*2);
  hbf16* iqkvb   = (hbf16*)alloc((size_t)2048*6144*2);   // pad region
  hbf16* tqkvb   = (hbf16*)alloc((size_t)256*6144*2);    // pad region
  hbf16* qb      = (hbf16*)alloc((size_t)2304*2048*2);
  hbf16* kb      = (hbf16*)alloc((size_t)2304*2048*2);
  hbf16* vb      = (hbf16*)alloc((size_t)2304*2048*2);
  hbf16* vtg     = (hbf16*)alloc((size_t)2048*2304*2);
  hbf16* attnb   = (hbf16*)alloc((size_t)2304*2048*2);
  float* img_mid = (float*)alloc((size_t)2048*2048*4);
  float* txt_mid = (float*)alloc((size_t)256*2048*4);
  hbf16* ix2     = (hbf16*)alloc((size_t)2048*2048*2);
  hbf16* tx2     = (hbf16*)alloc((size_t)256*2048*2);
  hbf16* h1i     = (hbf16*)alloc((size_t)2048*8192*2);
  hbf16* h1t     = (hbf16*)alloc((size_t)256*8192*2);
  float* mlp     = (float*)alloc((size_t)4*2304*16*2*4);
  (void)iqkvb; (void)tqkvb;
  hbf16* sop01 = (hbf16*)ix;
  hbf16* sop23 = (hbf16*)img_mid;

  // mod vectors (silu fused, img+txt in one dispatch pair)
  mod_part_k<<<dim3(12,32,2),256,0,stream>>>(vec, img_mod_w, txt_mod_w, part);
  mod_red_k<<<dim3(12,2),256,0,stream>>>(part, img_mod_b, txt_mod_b, im, tm);

  // pre-attn LN + modulate (fused img+txt)
  ln_mod_k<<<2304,256,0,stream>>>(img, txt, im+0, im+2048, tm+0, tm+2048, ix, tx);

  // qkv (fused img+txt), 256M tile, fused RMSNorm+RoPE epilogue -> qb/kb/vb
  transp3_k<<<dim3(96,16,2),256,0,stream>>>(img_qkv_w, wt1, txt_qkv_w, wt2, 2048, 6144);
  gemmqkv_k<<<432,512,0,stream>>>(ix, wt1, img_qn_w, img_kn_w, 0, 1,
                                  tx, wt2, txt_qn_w, txt_kn_w, 2048, 0,
                                  fcos, fsin, qb, kb, vb,
                                  48, 8, 1, 2048);

  // V transpose
  vtransp_k<<<dim3(36,32),256,0,stream>>>(vb, vtg);

  // attention (KV-split 4-way, bf16 partials) + merge
  attn_k<<<1152,512,0,stream>>>(qb, kb, vtg, sop01, sop23, mlp);
  amerge_k<<<2304,256,0,stream>>>(sop01, sop23, mlp, attnb);

  // proj + gate + residual (fused img+txt, BK=128)
  transp3_k<<<dim3(32,16,2),256,0,stream>>>(img_proj_w, wt1, txt_proj_w, wt2, 2048, 2048);
  gemmbk_k<2><<<288,256,0,stream>>>(attnb, wt1, img_mid, nullptr, im+4096, img,
                                    attnb + (size_t)2048*2048, wt2, txt_mid, nullptr, tm+4096, txt,
                                    16, 16, 2, 2048, 2048);

  // second LN + modulate (fused)
  ln_mod_k<<<2304,256,0,stream>>>(img_mid, txt_mid, im+6144, im+8192, tm+6144, tm+8192, ix2, tx2);

  // MLP fc1 (fused, 256M tile)
  transp3_k<<<dim3(128,16,2),256,0,stream>>>(img_fc1_w, wt1, txt_fc1_w, wt2, 2048, 8192);
  gemm256n_k<1><<<576,512,0,stream>>>(ix2, wt1, h1i, img_fc1_b,
                                      tx2, wt2, h1t, txt_fc1_b,
                                      64, 8, 1, 8192, 2048);

  // MLP fc2 (fused, BK=128)
  transp3_k<<<dim3(32,64,2),256,0,stream>>>(img_fc2_w, wt1, txt_fc2_w, wt2, 8192, 2048);
  gemmbk_k<3><<<288,256,0,stream>>>(h1i, wt1, out_img, img_fc2_b, im+10240, img_mid,
                                    h1t, wt2, out_txt, txt_fc2_b, tm+10240, txt_mid,
                                    16, 16, 2, 2048, 8192);
}

// Round 23
// 656.979 us; speedup vs baseline: 1.0324x; 1.0324x over previous
//
#include <hip/hip_runtime.h>
#include <hip/hip_bf16.h>
#include <cstdint>
#include <cstddef>

typedef __bf16 bf16x8 __attribute__((ext_vector_type(8)));
typedef float  f32x4  __attribute__((ext_vector_type(4)));
typedef __hip_bfloat16 hbf16;

#define DEVI static __device__ __forceinline__

DEVI unsigned short f2bf_bits(float x){
  hbf16 h = __float2bfloat16(x);
  return *reinterpret_cast<unsigned short*>(&h);
}
DEVI float gelu_tanh(float x){
  float u = x*(1.0f + 0.044715f*x*x);
  float t = exp2f(-2.3022119f*u);
  return x/(1.0f+t);
}

typedef __attribute__((address_space(1))) const unsigned int* gas_p;
typedef __attribute__((address_space(3))) unsigned int* las_p;
DEVI void gload16(const void* g, void* l){
  __builtin_amdgcn_global_load_lds((gas_p)g, (las_p)l, 16, 0, 0);
}

// ---------------- mod-vector GEMV (silu fused), dual-problem ----------------
__global__ __launch_bounds__(256) void mod_part_k(const float* __restrict__ vec_,
                                                  const float* __restrict__ W1,
                                                  const float* __restrict__ W2,
                                                  float* __restrict__ part){
  const float* W = blockIdx.z ? W2 : W1;
  float* po = part + (size_t)blockIdx.z*32*12288;
  int j  = blockIdx.x*1024 + threadIdx.x*4;
  int i0 = blockIdx.y*64;
  float4 acc = {0.f,0.f,0.f,0.f};
  for (int i=0;i<64;i++){
    float x = vec_[i0+i];
    float s = x/(1.0f+__expf(-x));        // silu fused
    float4 w = *(const float4*)(W + (size_t)(i0+i)*12288 + j);
    acc.x += s*w.x; acc.y += s*w.y; acc.z += s*w.z; acc.w += s*w.w;
  }
  *(float4*)(po + (size_t)blockIdx.y*12288 + j) = acc;
}

__global__ __launch_bounds__(256) void mod_red_k(const float* __restrict__ part,
                                                 const float* __restrict__ b1,
                                                 const float* __restrict__ b2,
                                                 float* __restrict__ out1,
                                                 float* __restrict__ out2){
  const float* p0 = part + (size_t)blockIdx.y*32*12288;
  const float* b  = blockIdx.y ? b2 : b1;
  float* out      = blockIdx.y ? out2 : out1;
  int j = blockIdx.x*1024 + threadIdx.x*4;
  float4 acc = *(const float4*)(b + j);
  #pragma unroll
  for (int y=0;y<32;y++){
    float4 p = *(const float4*)(p0 + (size_t)y*12288 + j);
    acc.x += p.x; acc.y += p.y; acc.z += p.z; acc.w += p.w;
  }
  *(float4*)(out + j) = acc;
}

// LayerNorm (no affine) + modulate -> bf16. Fused img + txt.
__global__ __launch_bounds__(256) void ln_mod_k(
    const float* __restrict__ Xi, const float* __restrict__ Xt,
    const float* __restrict__ sh_i, const float* __restrict__ sc_i,
    const float* __restrict__ sh_t, const float* __restrict__ sc_t,
    hbf16* __restrict__ Yi, hbf16* __restrict__ Yt){
  __shared__ float red[8];
  const int row = blockIdx.x, tid = threadIdx.x;
  const float* X; const float* sh; const float* sc; hbf16* Y; int r;
  if (row < 2048){ X = Xi; sh = sh_i; sc = sc_i; Y = Yi; r = row; }
  else           { X = Xt; sh = sh_t; sc = sc_t; Y = Yt; r = row - 2048; }
  const float* x = X + (size_t)r*2048;
  float4 a = *(const float4*)(x + tid*8);
  float4 c = *(const float4*)(x + tid*8 + 4);
  float s  = a.x+a.y+a.z+a.w + c.x+c.y+c.z+c.w;
  float s2 = a.x*a.x+a.y*a.y+a.z*a.z+a.w*a.w + c.x*c.x+c.y*c.y+c.z*c.z+c.w*c.w;
  #pragma unroll
  for (int m=1;m<64;m<<=1){ s += __shfl_xor(s,m,64); s2 += __shfl_xor(s2,m,64); }
  if ((tid&63)==0){ red[tid>>6] = s; red[4+(tid>>6)] = s2; }
  __syncthreads();
  float S  = red[0]+red[1]+red[2]+red[3];
  float S2 = red[4]+red[5]+red[6]+red[7];
  float mean = S*(1.f/2048.f);
  float var  = S2*(1.f/2048.f) - mean*mean;
  float rs = rsqrtf(var + 1e-6f);
  float xv[8] = {a.x,a.y,a.z,a.w,c.x,c.y,c.z,c.w};
  #pragma unroll
  for (int j=0;j<8;j++){
    int n = tid*8 + j;
    float yv = (xv[j]-mean)*rs*(1.f+sc[n]) + sh[n];
    Y[(size_t)r*2048 + n] = __float2bfloat16(yv);
  }
}

// transpose + fp32->bf16, fused img/txt pair: W [K][N] -> Wt [N][K].
__global__ __launch_bounds__(256) void transp3_k(const float* __restrict__ W1,
                                                 hbf16* __restrict__ Wt1,
                                                 const float* __restrict__ W2,
                                                 hbf16* __restrict__ Wt2,
                                                 int K, int N){
  const float* W = blockIdx.z ? W2 : W1;
  hbf16* Wt = blockIdx.z ? Wt2 : Wt1;
  __shared__ float tile[128][68];
  const int n0 = blockIdx.x*64, k0 = blockIdx.y*128;
  const int tid = threadIdx.x;
  #pragma unroll
  for (int i=0;i<8;i++){
    int c = i*256 + tid;
    int k = c>>4, nq = c&15;
    float4 v = *(const float4*)(W + (size_t)(k0+k)*N + n0 + nq*4);
    *(float4*)&tile[k][nq*4] = v;
  }
  __syncthreads();
  const int n = tid>>2, kseg = tid&3;
  unsigned short buf[32];
  #pragma unroll
  for (int j=0;j<32;j++) buf[j] = f2bf_bits(tile[kseg*32+j][n]);
  hbf16* dst = Wt + (size_t)(n0+n)*K + k0 + kseg*32;
  *(uint4*)(dst)      = *(const uint4*)&buf[0];
  *(uint4*)(dst + 8)  = *(const uint4*)&buf[8];
  *(uint4*)(dst + 16) = *(const uint4*)&buf[16];
  *(uint4*)(dst + 24) = *(const uint4*)&buf[24];
}

// bf16 transpose: V [2304][2048] -> Vt [2048][2304]
__global__ __launch_bounds__(256) void vtransp_k(const hbf16* __restrict__ V,
                                                 hbf16* __restrict__ Vt){
  __shared__ unsigned short tile[64][72];
  const int t0 = blockIdx.x*64, d0 = blockIdx.y*64;
  const int tid = threadIdx.x;
  #pragma unroll
  for (int i=0;i<2;i++){
    int c = i*256 + tid, row = c>>3, jj = c&7;
    uint4 v = *(const uint4*)(V + (size_t)(t0+row)*2048 + d0 + jj*8);
    *(uint4*)&tile[row][jj*8] = v;
  }
  __syncthreads();
  const int d = tid>>2, seg = tid&3;
  unsigned short buf[16];
  #pragma unroll
  for (int j=0;j<16;j++) buf[j] = tile[seg*16+j][d];
  *(uint4*)(Vt + (size_t)(d0+d)*2304 + t0 + seg*16)     = *(const uint4*)&buf[0];
  *(uint4*)(Vt + (size_t)(d0+d)*2304 + t0 + seg*16 + 8) = *(const uint4*)&buf[8];
}

// ---------------- GEMM 128^2, BK=128, dual-problem (proj / fc2) ----------------
// EPI: 2 fp32 res+gate*x, 3 fp32 res+gate*(x+bias).
template<int EPI>
__global__ __launch_bounds__(256,2) void gemmbk_k(
    const hbf16* __restrict__ A1, const hbf16* __restrict__ B1,
    float* __restrict__ Cf1, const float* __restrict__ bias1,
    const float* __restrict__ gate1, const float* __restrict__ res1,
    const hbf16* __restrict__ A2, const hbf16* __restrict__ B2,
    float* __restrict__ Cf2, const float* __restrict__ bias2,
    const float* __restrict__ gate2, const float* __restrict__ res2,
    int nbx, int nby1, int nby2, int N, int K)
{
  __shared__ unsigned short As[128*128];   // 32 KB
  __shared__ unsigned short Bs[128*128];   // 32 KB
  const int tid = threadIdx.x;
  const int wv = tid>>6, ln = tid&63;
  const int nwg = nbx*(nby1+nby2), q = nwg>>3;
  const int w  = blockIdx.x;
  const int w2 = (w&7)*q + (w>>3);
  int n0, m0;
  const hbf16* A; const hbf16* Bt; float* Cf;
  const float* bias; const float* gate; const float* res;
  if (w2 < nbx*nby1){
    n0 = (w2/nby1)*128; m0 = (w2%nby1)*128;
    A=A1; Bt=B1; Cf=Cf1; bias=bias1; gate=gate1; res=res1;
  } else {
    int w3 = w2 - nbx*nby1;
    n0 = (w3/nby2)*128; m0 = (w3%nby2)*128;
    A=A2; Bt=B2; Cf=Cf2; bias=bias2; gate=gate2; res=res2;
  }
  const int wm = (wv>>1)*64, wn = (wv&1)*64;
  const int lm = ln&15, lk = ln>>4;
  f32x4 acc[4][4];
  #pragma unroll
  for (int i=0;i<4;i++)
    #pragma unroll
    for (int j=0;j<4;j++) acc[i][j] = (f32x4){0.f,0.f,0.f,0.f};

  const int srow = tid>>4;                  // 0..15 (row mod 16)
  const int jsrc = (tid&15) ^ srow;         // involution partner of read swizzle
  const int NT = K>>7;

  for (int kt=0; kt<NT; ++kt){
    const int kk = kt<<7;
    #pragma unroll
    for (int i=0;i<8;i++){
      int row = i*16 + srow;
      gload16(A  + (size_t)(m0+row)*K + kk + jsrc*8, &As[(i*256+tid)*8]);
      gload16(Bt + (size_t)(n0+row)*K + kk + jsrc*8, &Bs[(i*256+tid)*8]);
    }
    __syncthreads();
    #pragma unroll
    for (int ks=0; ks<4; ++ks){
      bf16x8 af[4], bfv[4];
      #pragma unroll
      for (int qq=0;qq<4;qq++){
        int row = wm + qq*16 + lm;
        int jj  = ks*4 + lk;
        af[qq] = *(const bf16x8*)&As[row*128 + ((jj^(row&15))<<3)];
      }
      #pragma unroll
      for (int qq=0;qq<4;qq++){
        int row = wn + qq*16 + lm;
        int jj  = ks*4 + lk;
        bfv[qq] = *(const bf16x8*)&Bs[row*128 + ((jj^(row&15))<<3)];
      }
      #pragma unroll
      for (int i=0;i<4;i++)
        #pragma unroll
        for (int j=0;j<4;j++)
          acc[i][j] = __builtin_amdgcn_mfma_f32_16x16x32_bf16(af[i], bfv[j], acc[i][j], 0,0,0);
    }
    __syncthreads();
  }
  #pragma unroll
  for (int i=0;i<4;i++){
    int mbase = m0 + wm + i*16 + lk*4;
    #pragma unroll
    for (int j=0;j<4;j++){
      int n = n0 + wn + j*16 + lm;
      #pragma unroll
      for (int r=0;r<4;r++){
        size_t idx = (size_t)(mbase+r)*N + n;
        float v = acc[i][j][r];
        if constexpr (EPI==2){ Cf[idx] = res[idx] + gate[n]*v; }
        else { Cf[idx] = res[idx] + gate[n]*(v + bias[n]); }
      }
    }
  }
}

// ---------------- GEMM 256Mx128N, 8 waves, per-wave 64x64 (fc1) ----------------
template<int EPI>
__global__ __launch_bounds__(512) void gemm256n_k(
    const hbf16* __restrict__ A1, const hbf16* __restrict__ B1,
    hbf16* __restrict__ Cb1, const float* __restrict__ bias1,
    const hbf16* __restrict__ A2, const hbf16* __restrict__ B2,
    hbf16* __restrict__ Cb2, const float* __restrict__ bias2,
    int nbx, int nby1, int nby2, int N, int K)
{
  __shared__ unsigned short As[256*64];   // 32 KB
  __shared__ unsigned short Bs[128*64];   // 16 KB
  const int tid = threadIdx.x;
  const int wv = tid>>6, ln = tid&63;
  const int nwg = nbx*(nby1+nby2), q = nwg>>3;
  const int w  = blockIdx.x;
  const int w2 = (w&7)*q + (w>>3);
  int n0, m0;
  const hbf16* A; const hbf16* Bt; hbf16* Cb; const float* bias;
  if (w2 < nbx*nby1){
    n0 = (w2/nby1)*128; m0 = (w2%nby1)*256;
    A=A1; Bt=B1; Cb=Cb1; bias=bias1;
  } else {
    int w3 = w2 - nbx*nby1;
    n0 = (w3/nby2)*128; m0 = (w3%nby2)*256;
    A=A2; Bt=B2; Cb=Cb2; bias=bias2;
  }
  const int wm = wv>>1, wn = wv&1;       // 4M x 2N waves
  const int lm = ln&15, lk = ln>>4;
  f32x4 acc[4][4];
  #pragma unroll
  for (int i=0;i<4;i++)
    #pragma unroll
    for (int j=0;j<4;j++) acc[i][j] = (f32x4){0.f,0.f,0.f,0.f};

  const int srow = tid>>3;               // 0..63
  const int jsrc = (tid&7) ^ (srow&7);
  const int NT = K>>6;

  for (int kt=0; kt<NT; ++kt){
    const int kk = kt<<6;
    #pragma unroll
    for (int i=0;i<4;i++)
      gload16(A + (size_t)(m0 + i*64 + srow)*K + kk + jsrc*8, &As[(i*512+tid)*8]);
    #pragma unroll
    for (int i=0;i<2;i++)
      gload16(Bt + (size_t)(n0 + i*64 + srow)*K + kk + jsrc*8, &Bs[(i*512+tid)*8]);
    __syncthreads();
    #pragma unroll
    for (int ks=0; ks<2; ++ks){
      bf16x8 af[4], bfv[4];
      #pragma unroll
      for (int qq=0;qq<4;qq++){
        int row = wm*64 + qq*16 + lm;
        int jj  = ks*4 + lk;
        af[qq] = *(const bf16x8*)&As[row*64 + ((jj^(row&7))<<3)];
      }
      #pragma unroll
      for (int qq=0;qq<4;qq++){
        int row = wn*64 + qq*16 + lm;
        int jj  = ks*4 + lk;
        bfv[qq] = *(const bf16x8*)&Bs[row*64 + ((jj^(row&7))<<3)];
      }
      #pragma unroll
      for (int i=0;i<4;i++)
        #pragma unroll
        for (int j=0;j<4;j++)
          acc[i][j] = __builtin_amdgcn_mfma_f32_16x16x32_bf16(af[i], bfv[j], acc[i][j], 0,0,0);
    }
    __syncthreads();
  }
  #pragma unroll
  for (int i=0;i<4;i++){
    int mbase = m0 + wm*64 + i*16 + lk*4;
    #pragma unroll
    for (int j=0;j<4;j++){
      int n = n0 + wn*64 + j*16 + lm;
      #pragma unroll
      for (int r=0;r<4;r++){
        size_t idx = (size_t)(mbase+r)*N + n;
        float v = acc[i][j][r];
        if constexpr (EPI==1){ Cb[idx] = __float2bfloat16(gelu_tanh(v + bias[n])); }
        else { Cb[idx] = __float2bfloat16(v); }
      }
    }
  }
}

// ---------------- qkv GEMM 256Mx128N with fused RMSNorm + RoPE epilogue ----------------
__global__ __launch_bounds__(512) void gemmqkv_k(
    const hbf16* __restrict__ A1, const hbf16* __restrict__ B1,
    const float* __restrict__ qn1, const float* __restrict__ kn1,
    int tok1, int rope1,
    const hbf16* __restrict__ A2, const hbf16* __restrict__ B2,
    const float* __restrict__ qn2, const float* __restrict__ kn2,
    int tok2, int rope2,
    const float* __restrict__ fcos_, const float* __restrict__ fsin_,
    hbf16* __restrict__ qb, hbf16* __restrict__ kb, hbf16* __restrict__ vb,
    int nbx, int nby1, int nby2, int K)
{
  __shared__ unsigned short As[256*64];
  __shared__ unsigned short Bs[128*64];
  __shared__ float ssb[2][256];
  const int tid = threadIdx.x;
  const int wv = tid>>6, ln = tid&63;
  const int nwg = nbx*(nby1+nby2), q = nwg>>3;
  const int w  = blockIdx.x;
  const int w2 = (w&7)*q + (w>>3);
  int n0, m0, tok, dorope;
  const hbf16* A; const hbf16* Bt; const float* qn; const float* kn;
  if (w2 < nbx*nby1){
    n0 = (w2/nby1)*128; m0 = (w2%nby1)*256;
    A=A1; Bt=B1; qn=qn1; kn=kn1; tok=tok1; dorope=rope1;
  } else {
    int w3 = w2 - nbx*nby1;
    n0 = (w3/nby2)*128; m0 = (w3%nby2)*256;
    A=A2; Bt=B2; qn=qn2; kn=kn2; tok=tok2; dorope=rope2;
  }
  const int wm = wv>>1, wn = wv&1;
  const int lm = ln&15, lk = ln>>4;
  f32x4 acc[4][4];
  #pragma unroll
  for (int i=0;i<4;i++)
    #pragma unroll
    for (int j=0;j<4;j++) acc[i][j] = (f32x4){0.f,0.f,0.f,0.f};

  const int srow = tid>>3;
  const int jsrc = (tid&7) ^ (srow&7);
  const int NT = K>>6;

  for (int kt=0; kt<NT; ++kt){
    const int kk = kt<<6;
    #pragma unroll
    for (int i=0;i<4;i++)
      gload16(A + (size_t)(m0 + i*64 + srow)*K + kk + jsrc*8, &As[(i*512+tid)*8]);
    #pragma unroll
    for (int i=0;i<2;i++)
      gload16(Bt + (size_t)(n0 + i*64 + srow)*K + kk + jsrc*8, &Bs[(i*512+tid)*8]);
    __syncthreads();
    #pragma unroll
    for (int ks=0; ks<2; ++ks){
      bf16x8 af[4], bfv[4];
      #pragma unroll
      for (int qq=0;qq<4;qq++){
        int row = wm*64 + qq*16 + lm;
        int jj  = ks*4 + lk;
        af[qq] = *(const bf16x8*)&As[row*64 + ((jj^(row&7))<<3)];
      }
      #pragma unroll
      for (int qq=0;qq<4;qq++){
        int row = wn*64 + qq*16 + lm;
        int jj  = ks*4 + lk;
        bfv[qq] = *(const bf16x8*)&Bs[row*64 + ((jj^(row&7))<<3)];
      }
      #pragma unroll
      for (int i=0;i<4;i++)
        #pragma unroll
        for (int j=0;j<4;j++)
          acc[i][j] = __builtin_amdgcn_mfma_f32_16x16x32_bf16(af[i], bfv[j], acc[i][j], 0,0,0);
    }
    __syncthreads();
  }

  const int which = n0 >> 11;        // 0:q 1:k 2:v
  const int head  = (n0 >> 7) & 15;
  if (which == 2){
    #pragma unroll
    for (int i=0;i<4;i++){
      int mbase = m0 + wm*64 + i*16 + lk*4;
      #pragma unroll
      for (int j=0;j<4;j++){
        int d = wn*64 + j*16 + lm;
        #pragma unroll
        for (int r=0;r<4;r++)
          vb[(size_t)(tok + mbase + r)*2048 + head*128 + d] = __float2bfloat16(acc[i][j][r]);
      }
    }
  } else {
    #pragma unroll
    for (int i=0;i<4;i++){
      #pragma unroll
      for (int r=0;r<4;r++){
        float p = 0.f;
        #pragma unroll
        for (int j=0;j<4;j++) p += acc[i][j][r]*acc[i][j][r];
        #pragma unroll
        for (int msk=1; msk<16; msk<<=1) p += __shfl_xor(p, msk, 64);
        if (lm == 0) ssb[wn][wm*64 + i*16 + lk*4 + r] = p;
      }
    }
    __syncthreads();
    const float* wgt = (which==0) ? qn : kn;
    const float qs = (which==0) ? 0.12751745f : 1.0f;   // 1/sqrt(128)*log2e for q
    hbf16* outb = (which==0) ? qb : kb;
    #pragma unroll
    for (int i=0;i<4;i++){
      #pragma unroll
      for (int r=0;r<4;r++){
        int row = wm*64 + i*16 + lk*4 + r;
        float ss = ssb[0][row] + ssb[1][row];
        float rs = rsqrtf(ss*(1.f/128.f) + 1e-6f) * qs;
        int t = m0 + row;
        #pragma unroll
        for (int j=0;j<4;j++){
          int d = wn*64 + j*16 + lm;
          float z = acc[i][j][r]*rs*wgt[d];
          float zp = __shfl_xor(z, 1, 64);
          float out;
          if (dorope){
            float c = fcos_[(size_t)t*128 + d];
            float s = fsin_[(size_t)t*128 + d];
            out = ((d&1)==0) ? (z*c - zp*s) : (z*c + zp*s);
          } else out = z;
          outb[(size_t)(tok + t)*2048 + head*128 + d] = __float2bfloat16(out);
        }
      }
    }
  }
}

// ---------------- flash attention: KV-split 4-way, bf16 partials ----------------
__global__ __launch_bounds__(512,4) void attn_k(
    const hbf16* __restrict__ Qg, const hbf16* __restrict__ Kg,
    const hbf16* __restrict__ Vtg, hbf16* __restrict__ sop01,
    hbf16* __restrict__ sop23, float* __restrict__ mlp)
{
  const int w = blockIdx.x;
  const int h = w & 15, quarter = (w>>4)&3, q0 = (w>>6)*128;
  const int tid = threadIdx.x, wv = tid>>6, ln = tid&63;
  __shared__ unsigned short Ks[2][64*128];
  __shared__ unsigned short Vs[2][128*64];
  __shared__ unsigned short Ps[8][16*64];

  bf16x8 qf[4];
  {
    const hbf16* qrow = Qg + (size_t)(q0 + wv*16 + (ln&15))*2048 + h*128 + (ln>>4)*8;
    #pragma unroll
    for (int ks=0;ks<4;ks++) qf[ks] = *(const bf16x8*)(qrow + ks*32);
  }

  f32x4 so[8];
  #pragma unroll
  for (int i=0;i<8;i++) so[i] = (f32x4){0.f,0.f,0.f,0.f};
  float m_run[4] = {-3e38f,-3e38f,-3e38f,-3e38f};
  float l_run[4] = {0.f,0.f,0.f,0.f};

  auto stage = [&](int buf, int kt){
    const int k0 = kt*64;
    #pragma unroll
    for (int i=0;i<2;i++){
      int c = i*512 + tid;
      int row = c>>4, jj = c&15;
      int js = jj ^ (row&7);
      gload16(Kg + (size_t)(k0+row)*2048 + h*128 + js*8, &Ks[buf][(i*512 + wv*64)*8]);
    }
    #pragma unroll
    for (int i=0;i<2;i++){
      int c = i*512 + tid;
      int row = c>>3, jj = c&7;
      int js = jj ^ (row&7);
      gload16(Vtg + (size_t)(h*128+row)*2304 + k0 + js*8, &Vs[buf][(i*512 + wv*64)*8]);
    }
  };

  const int t0 = quarter*9;
  stage(0, t0);
  __syncthreads();

  for (int it=0; it<9; ++it){
    const int cur = it&1;
    if (it+1 < 9) stage(cur^1, t0+it+1);

    f32x4 s[4];
    #pragma unroll
    for (int nb=0;nb<4;nb++) s[nb] = (f32x4){0.f,0.f,0.f,0.f};
    __builtin_amdgcn_s_setprio(1);
    #pragma unroll
    for (int ks=0;ks<4;ks++){
      #pragma unroll
      for (int nb=0;nb<4;nb++){
        int rk = nb*16 + (ln&15);
        int jq = ks*4 + (ln>>4);
        bf16x8 bk = *(const bf16x8*)&Ks[cur][rk*128 + ((jq^(rk&7))<<3)];
        s[nb] = __builtin_amdgcn_mfma_f32_16x16x32_bf16(qf[ks], bk, s[nb], 0,0,0);
      }
    }
    __builtin_amdgcn_s_setprio(0);

    float scl[4];
    #pragma unroll
    for (int r=0;r<4;r++){
      float m1 = fmaxf(fmaxf(s[0][r], s[1][r]), fmaxf(s[2][r], s[3][r]));
      #pragma unroll
      for (int msk=1; msk<16; msk<<=1) m1 = fmaxf(m1, __shfl_xor(m1, msk, 64));
      float mn = fmaxf(m_run[r], m1);
      scl[r] = exp2f(m_run[r] - mn);
      m_run[r] = mn;
    }
    #pragma unroll
    for (int nb=0;nb<4;nb++)
      #pragma unroll
      for (int r=0;r<4;r++)
        s[nb][r] = exp2f(s[nb][r] - m_run[r]);
    #pragma unroll
    for (int r=0;r<4;r++){
      float sm = s[0][r]+s[1][r]+s[2][r]+s[3][r];
      #pragma unroll
      for (int msk=1; msk<16; msk<<=1) sm += __shfl_xor(sm, msk, 64);
      l_run[r] = l_run[r]*scl[r] + sm;
    }
    #pragma unroll
    for (int nb2=0;nb2<8;nb2++)
      #pragma unroll
      for (int r=0;r<4;r++) so[nb2][r] *= scl[r];

    #pragma unroll
    for (int nb=0;nb<4;nb++)
      #pragma unroll
      for (int r=0;r<4;r++){
        int m = ((ln>>4)<<2) + r;
        int n = nb*16 + (ln&15);
        Ps[wv][m*64 + (((n>>3)^(m&7))<<3) + (n&7)] = f2bf_bits(s[nb][r]);
      }

    __builtin_amdgcn_s_setprio(1);
    #pragma unroll
    for (int ks=0;ks<2;ks++){
      int mrow = ln&15;
      bf16x8 pa = *(const bf16x8*)&Ps[wv][mrow*64 + (((ks*4+(ln>>4))^(mrow&7))<<3)];
      #pragma unroll
      for (int nb2=0;nb2<8;nb2++){
        int rv = nb2*16 + (ln&15);
        int jv = ks*4 + (ln>>4);
        bf16x8 bv = *(const bf16x8*)&Vs[cur][rv*64 + ((jv^(rv&7))<<3)];
        so[nb2] = __builtin_amdgcn_mfma_f32_16x16x32_bf16(pa, bv, so[nb2], 0,0,0);
      }
    }
    __builtin_amdgcn_s_setprio(0);
    __syncthreads();
  }

  hbf16* sbase = (quarter < 2 ? sop01 + (size_t)quarter*2304*2048
                              : sop23 + (size_t)(quarter-2)*2304*2048);
  #pragma unroll
  for (int r=0;r<4;r++){
    int m = q0 + wv*16 + ((ln>>4)<<2) + r;
    #pragma unroll
    for (int nb2=0;nb2<8;nb2++){
      int d = h*128 + nb2*16 + (ln&15);
      sbase[(size_t)m*2048 + d] = __float2bfloat16(so[nb2][r]);
    }
  }
  if ((ln&15)==0){
    #pragma unroll
    for (int r=0;r<4;r++){
      int m = q0 + wv*16 + ((ln>>4)<<2) + r;
      float* p = mlp + ((size_t)(quarter*2304 + m)*16 + h)*2;
      p[0] = m_run[r]; p[1] = l_run[r];
    }
  }
}

// merge the 4 KV quarters (bf16 partials)
__global__ __launch_bounds__(256) void amerge_k(const hbf16* __restrict__ sop01,
                                                const hbf16* __restrict__ sop23,
                                                const float* __restrict__ mlp,
                                                hbf16* __restrict__ Og){
  const int q = blockIdx.x, tid = threadIdx.x;
  const int d0 = tid*8, h = tid>>4;
  float mv[4], lv[4];
  float m = -3e38f;
  #pragma unroll
  for (int h4=0;h4<4;h4++){
    const float* p = mlp + ((size_t)(h4*2304 + q)*16 + h)*2;
    mv[h4] = p[0]; lv[h4] = p[1];
    m = fmaxf(m, mv[h4]);
  }
  float wgt[4], den = 0.f;
  #pragma unroll
  for (int h4=0;h4<4;h4++){ wgt[h4] = exp2f(mv[h4]-m); den += wgt[h4]*lv[h4]; }
  float inv = 1.0f/den;
  float acc[8] = {0,0,0,0,0,0,0,0};
  #pragma unroll
  for (int h4=0;h4<4;h4++){
    const hbf16* s = (h4<2 ? sop01 + (size_t)h4*2304*2048
                           : sop23 + (size_t)(h4-2)*2304*2048) + (size_t)q*2048 + d0;
    bf16x8 v = *(const bf16x8*)s;
    #pragma unroll
    for (int j=0;j<8;j++) acc[j] += wgt[h4]*(float)v[j];
  }
  hbf16* o = Og + (size_t)q*2048 + d0;
  #pragma unroll
  for (int j=0;j<8;j++) o[j] = __float2bfloat16(acc[j]*inv);
}

// ---------------- launcher ----------------

extern "C" void kernel_launch(void* const* d_in, const int* in_sizes, int n_in,
                              void* d_out, int out_size, void* d_ws, size_t ws_size,
                              hipStream_t stream) {
  (void)in_sizes; (void)n_in; (void)out_size; (void)ws_size;
  const float* img   = (const float*)d_in[0];
  const float* txt   = (const float*)d_in[1];
  const float* vec   = (const float*)d_in[2];
  const float* fcos  = (const float*)d_in[3];
  const float* fsin  = (const float*)d_in[4];
  const float* img_mod_w = (const float*)d_in[6];
  const float* img_mod_b = (const float*)d_in[7];
  const float* img_qkv_w = (const float*)d_in[8];
  const float* img_qn_w  = (const float*)d_in[9];
  const float* img_kn_w  = (const float*)d_in[10];
  const float* img_proj_w= (const float*)d_in[11];
  const float* img_fc1_w = (const float*)d_in[12];
  const float* img_fc1_b = (const float*)d_in[13];
  const float* img_fc2_w = (const float*)d_in[14];
  const float* img_fc2_b = (const float*)d_in[15];
  const float* txt_mod_w = (const float*)d_in[16];
  const float* txt_mod_b = (const float*)d_in[17];
  const float* txt_qkv_w = (const float*)d_in[18];
  const float* txt_qn_w  = (const float*)d_in[19];
  const float* txt_kn_w  = (const float*)d_in[20];
  const float* txt_proj_w= (const float*)d_in[21];
  const float* txt_fc1_w = (const float*)d_in[22];
  const float* txt_fc1_b = (const float*)d_in[23];
  const float* txt_fc2_w = (const float*)d_in[24];
  const float* txt_fc2_b = (const float*)d_in[25];

  float* out_img = (float*)d_out;
  float* out_txt = out_img + (size_t)2048*2048;

  char* ws = (char*)d_ws;
  size_t off = 0;
  auto alloc = [&](size_t bytes)->void*{
    void* p = ws + off; off += (bytes + 255) & ~(size_t)255; return p;
  };
  hbf16* wt1     = (hbf16*)alloc((size_t)16777216*2);
  hbf16* wt2     = (hbf16*)alloc((size_t)16777216*2);
  float* im      = (float*)alloc(12288*4);
  float* tm      = (float*)alloc(12288*4);
  float* part    = (float*)alloc((size_t)2*32*12288*4);
  // ix..tqkvb contiguous region later reused as sop01 (bf16 partials).
  hbf16* ix      = (hbf16*)alloc((size_t)2048*2048*2);
  hbf16* tx      = (hbf16*)alloc((size_t)256*2048*2);
  hbf16* iqkvb   = (hbf16*)alloc((size_t)2048*6144*2);   // pad region
  hbf16* tqkvb   = (hbf16*)alloc((size_t)256*6144*2);    // pad region
  hbf16* qb      = (hbf16*)alloc((size_t)2304*2048*2);
  hbf16* kb      = (hbf16*)alloc((size_t)2304*2048*2);
  hbf16* vb      = (hbf16*)alloc((size_t)2304*2048*2);
  hbf16* vtg     = (hbf16*)alloc((size_t)2048*2304*2);
  hbf16* attnb   = (hbf16*)alloc((size_t)2304*2048*2);
  float* img_mid = (float*)alloc((size_t)2048*2048*4);
  float* txt_mid = (float*)alloc((size_t)256*2048*4);
  hbf16* ix2     = (hbf16*)alloc((size_t)2048*2048*2);
  hbf16* tx2     = (hbf16*)alloc((size_t)256*2048*2);
  hbf16* h1i     = (hbf16*)alloc((size_t)2048*8192*2);
  hbf16* h1t     = (hbf16*)alloc((size_t)256*8192*2);
  float* mlp     = (float*)alloc((size_t)4*2304*16*2*4);
  (void)iqkvb; (void)tqkvb;
  hbf16* sop01 = (hbf16*)ix;
  hbf16* sop23 = (hbf16*)img_mid;

  // mod vectors (silu fused, img+txt in one dispatch pair)
  mod_part_k<<<dim3(12,32,2),256,0,stream>>>(vec, img_mod_w, txt_mod_w, part);
  mod_red_k<<<dim3(12,2),256,0,stream>>>(part, img_mod_b, txt_mod_b, im, tm);

  // pre-attn LN + modulate (fused img+txt)
  ln_mod_k<<<2304,256,0,stream>>>(img, txt, im+0, im+2048, tm+0, tm+2048, ix, tx);

  // qkv (fused img+txt), 256M tile, fused RMSNorm+RoPE epilogue -> qb/kb/vb
  transp3_k<<<dim3(96,16,2),256,0,stream>>>(img_qkv_w, wt1, txt_qkv_w, wt2, 2048, 6144);
  gemmqkv_k<<<432,512,0,stream>>>(ix, wt1, img_qn_w, img_kn_w, 0, 1,
                                  tx, wt2, txt_qn_w, txt_kn_w, 2048, 0,
                                  fcos, fsin, qb, kb, vb,
                                  48, 8, 1, 2048);

  // V transpose
  vtransp_k<<<dim3(36,32),256,0,stream>>>(vb, vtg);

  // attention (KV-split 4-way, bf16 partials) + merge
  attn_k<<<1152,512,0,stream>>>(qb, kb, vtg, sop01, sop23, mlp);
  amerge_k<<<2304,256,0,stream>>>(sop01, sop23, mlp, attnb);

  // proj + gate + residual (fused img+txt, BK=128)
  transp3_k<<<dim3(32,16,2),256,0,stream>>>(img_proj_w, wt1, txt_proj_w, wt2, 2048, 2048);
  gemmbk_k<2><<<288,256,0,stream>>>(attnb, wt1, img_mid, nullptr, im+4096, img,
                                    attnb + (size_t)2048*2048, wt2, txt_mid, nullptr, tm+4096, txt,
                                    16, 16, 2, 2048, 2048);

  // second LN + modulate (fused)
  ln_mod_k<<<2304,256,0,stream>>>(img_mid, txt_mid, im+6144, im+8192, tm+6144, tm+8192, ix2, tx2);

  // MLP fc1 (fused, 256M tile)
  transp3_k<<<dim3(128,16,2),256,0,stream>>>(img_fc1_w, wt1, txt_fc1_w, wt2, 2048, 8192);
  gemm256n_k<1><<<576,512,0,stream>>>(ix2, wt1, h1i, img_fc1_b,
                                      tx2, wt2, h1t, txt_fc1_b,
                                      64, 8, 1, 8192, 2048);

  // MLP fc2 (fused, BK=128)
  transp3_k<<<dim3(32,64,2),256,0,stream>>>(img_fc2_w, wt1, txt_fc2_w, wt2, 8192, 2048);
  gemmbk_k<3><<<288,256,0,stream>>>(h1i, wt1, out_img, img_fc2_b, im+10240, img_mid,
                                    h1t, wt2, out_txt, txt_fc2_b, tm+10240, txt_mid,
                                    16, 16, 2, 2048, 8192);
}

// Round 24
// 656.521 us; speedup vs baseline: 1.0332x; 1.0007x over previous
//
#include <hip/hip_runtime.h>
#include <hip/hip_bf16.h>
#include <cstdint>
#include <cstddef>

typedef __bf16 bf16x8 __attribute__((ext_vector_type(8)));
typedef float  f32x4  __attribute__((ext_vector_type(4)));
typedef __hip_bfloat16 hbf16;

#define DEVI static __device__ __forceinline__

DEVI unsigned short f2bf_bits(float x){
  hbf16 h = __float2bfloat16(x);
  return *reinterpret_cast<unsigned short*>(&h);
}
DEVI float gelu_tanh(float x){
  float u = x*(1.0f + 0.044715f*x*x);
  float t = exp2f(-2.3022119f*u);
  return x/(1.0f+t);
}

typedef __attribute__((address_space(1))) const unsigned int* gas_p;
typedef __attribute__((address_space(3))) unsigned int* las_p;
DEVI void gload16(const void* g, void* l){
  __builtin_amdgcn_global_load_lds((gas_p)g, (las_p)l, 16, 0, 0);
}

// ---------------- mod-vector GEMV (silu fused), dual-problem ----------------
__global__ __launch_bounds__(256) void mod_part_k(const float* __restrict__ vec_,
                                                  const float* __restrict__ W1,
                                                  const float* __restrict__ W2,
                                                  float* __restrict__ part){
  const float* W = blockIdx.z ? W2 : W1;
  float* po = part + (size_t)blockIdx.z*32*12288;
  int j  = blockIdx.x*1024 + threadIdx.x*4;
  int i0 = blockIdx.y*64;
  float4 acc = {0.f,0.f,0.f,0.f};
  for (int i=0;i<64;i++){
    float x = vec_[i0+i];
    float s = x/(1.0f+__expf(-x));        // silu fused
    float4 w = *(const float4*)(W + (size_t)(i0+i)*12288 + j);
    acc.x += s*w.x; acc.y += s*w.y; acc.z += s*w.z; acc.w += s*w.w;
  }
  *(float4*)(po + (size_t)blockIdx.y*12288 + j) = acc;
}

__global__ __launch_bounds__(256) void mod_red_k(const float* __restrict__ part,
                                                 const float* __restrict__ b1,
                                                 const float* __restrict__ b2,
                                                 float* __restrict__ out1,
                                                 float* __restrict__ out2){
  const float* p0 = part + (size_t)blockIdx.y*32*12288;
  const float* b  = blockIdx.y ? b2 : b1;
  float* out      = blockIdx.y ? out2 : out1;
  int j = blockIdx.x*1024 + threadIdx.x*4;
  float4 acc = *(const float4*)(b + j);
  #pragma unroll
  for (int y=0;y<32;y++){
    float4 p = *(const float4*)(p0 + (size_t)y*12288 + j);
    acc.x += p.x; acc.y += p.y; acc.z += p.z; acc.w += p.w;
  }
  *(float4*)(out + j) = acc;
}

// LayerNorm (no affine) + modulate -> bf16. Fused img + txt.
__global__ __launch_bounds__(256) void ln_mod_k(
    const float* __restrict__ Xi, const float* __restrict__ Xt,
    const float* __restrict__ sh_i, const float* __restrict__ sc_i,
    const float* __restrict__ sh_t, const float* __restrict__ sc_t,
    hbf16* __restrict__ Yi, hbf16* __restrict__ Yt){
  __shared__ float red[8];
  const int row = blockIdx.x, tid = threadIdx.x;
  const float* X; const float* sh; const float* sc; hbf16* Y; int r;
  if (row < 2048){ X = Xi; sh = sh_i; sc = sc_i; Y = Yi; r = row; }
  else           { X = Xt; sh = sh_t; sc = sc_t; Y = Yt; r = row - 2048; }
  const float* x = X + (size_t)r*2048;
  float4 a = *(const float4*)(x + tid*8);
  float4 c = *(const float4*)(x + tid*8 + 4);
  float s  = a.x+a.y+a.z+a.w + c.x+c.y+c.z+c.w;
  float s2 = a.x*a.x+a.y*a.y+a.z*a.z+a.w*a.w + c.x*c.x+c.y*c.y+c.z*c.z+c.w*c.w;
  #pragma unroll
  for (int m=1;m<64;m<<=1){ s += __shfl_xor(s,m,64); s2 += __shfl_xor(s2,m,64); }
  if ((tid&63)==0){ red[tid>>6] = s; red[4+(tid>>6)] = s2; }
  __syncthreads();
  float S  = red[0]+red[1]+red[2]+red[3];
  float S2 = red[4]+red[5]+red[6]+red[7];
  float mean = S*(1.f/2048.f);
  float var  = S2*(1.f/2048.f) - mean*mean;
  float rs = rsqrtf(var + 1e-6f);
  float xv[8] = {a.x,a.y,a.z,a.w,c.x,c.y,c.z,c.w};
  #pragma unroll
  for (int j=0;j<8;j++){
    int n = tid*8 + j;
    float yv = (xv[j]-mean)*rs*(1.f+sc[n]) + sh[n];
    Y[(size_t)r*2048 + n] = __float2bfloat16(yv);
  }
}

// transpose + fp32->bf16, fused img/txt pair: W [K][N] -> Wt [N][K].
__global__ __launch_bounds__(256) void transp3_k(const float* __restrict__ W1,
                                                 hbf16* __restrict__ Wt1,
                                                 const float* __restrict__ W2,
                                                 hbf16* __restrict__ Wt2,
                                                 int K, int N){
  const float* W = blockIdx.z ? W2 : W1;
  hbf16* Wt = blockIdx.z ? Wt2 : Wt1;
  __shared__ float tile[128][68];
  const int n0 = blockIdx.x*64, k0 = blockIdx.y*128;
  const int tid = threadIdx.x;
  #pragma unroll
  for (int i=0;i<8;i++){
    int c = i*256 + tid;
    int k = c>>4, nq = c&15;
    float4 v = *(const float4*)(W + (size_t)(k0+k)*N + n0 + nq*4);
    *(float4*)&tile[k][nq*4] = v;
  }
  __syncthreads();
  const int n = tid>>2, kseg = tid&3;
  unsigned short buf[32];
  #pragma unroll
  for (int j=0;j<32;j++) buf[j] = f2bf_bits(tile[kseg*32+j][n]);
  hbf16* dst = Wt + (size_t)(n0+n)*K + k0 + kseg*32;
  *(uint4*)(dst)      = *(const uint4*)&buf[0];
  *(uint4*)(dst + 8)  = *(const uint4*)&buf[8];
  *(uint4*)(dst + 16) = *(const uint4*)&buf[16];
  *(uint4*)(dst + 24) = *(const uint4*)&buf[24];
}

// bf16 transpose: V [2304][2048] -> Vt [2048][2304]
__global__ __launch_bounds__(256) void vtransp_k(const hbf16* __restrict__ V,
                                                 hbf16* __restrict__ Vt){
  __shared__ unsigned short tile[64][72];
  const int t0 = blockIdx.x*64, d0 = blockIdx.y*64;
  const int tid = threadIdx.x;
  #pragma unroll
  for (int i=0;i<2;i++){
    int c = i*256 + tid, row = c>>3, jj = c&7;
    uint4 v = *(const uint4*)(V + (size_t)(t0+row)*2048 + d0 + jj*8);
    *(uint4*)&tile[row][jj*8] = v;
  }
  __syncthreads();
  const int d = tid>>2, seg = tid&3;
  unsigned short buf[16];
  #pragma unroll
  for (int j=0;j<16;j++) buf[j] = tile[seg*16+j][d];
  *(uint4*)(Vt + (size_t)(d0+d)*2304 + t0 + seg*16)     = *(const uint4*)&buf[0];
  *(uint4*)(Vt + (size_t)(d0+d)*2304 + t0 + seg*16 + 8) = *(const uint4*)&buf[8];
}

// ---------------- GEMM 128^2, BK=128, dual-problem (proj / fc2) ----------------
// EPI: 2 fp32 res+gate*x, 3 fp32 res+gate*(x+bias).
template<int EPI>
__global__ __launch_bounds__(256,2) void gemmbk_k(
    const hbf16* __restrict__ A1, const hbf16* __restrict__ B1,
    float* __restrict__ Cf1, const float* __restrict__ bias1,
    const float* __restrict__ gate1, const float* __restrict__ res1,
    const hbf16* __restrict__ A2, const hbf16* __restrict__ B2,
    float* __restrict__ Cf2, const float* __restrict__ bias2,
    const float* __restrict__ gate2, const float* __restrict__ res2,
    int nbx, int nby1, int nby2, int N, int K)
{
  __shared__ unsigned short As[128*128];   // 32 KB
  __shared__ unsigned short Bs[128*128];   // 32 KB
  const int tid = threadIdx.x;
  const int wv = tid>>6, ln = tid&63;
  const int nwg = nbx*(nby1+nby2), q = nwg>>3;
  const int w  = blockIdx.x;
  const int w2 = (w&7)*q + (w>>3);
  int n0, m0;
  const hbf16* A; const hbf16* Bt; float* Cf;
  const float* bias; const float* gate; const float* res;
  if (w2 < nbx*nby1){
    n0 = (w2/nby1)*128; m0 = (w2%nby1)*128;
    A=A1; Bt=B1; Cf=Cf1; bias=bias1; gate=gate1; res=res1;
  } else {
    int w3 = w2 - nbx*nby1;
    n0 = (w3/nby2)*128; m0 = (w3%nby2)*128;
    A=A2; Bt=B2; Cf=Cf2; bias=bias2; gate=gate2; res=res2;
  }
  const int wm = (wv>>1)*64, wn = (wv&1)*64;
  const int lm = ln&15, lk = ln>>4;
  f32x4 acc[4][4];
  #pragma unroll
  for (int i=0;i<4;i++)
    #pragma unroll
    for (int j=0;j<4;j++) acc[i][j] = (f32x4){0.f,0.f,0.f,0.f};

  const int srow = tid>>4;                  // 0..15 (row mod 16)
  const int jsrc = (tid&15) ^ srow;         // involution partner of read swizzle
  const int NT = K>>7;

  for (int kt=0; kt<NT; ++kt){
    const int kk = kt<<7;
    #pragma unroll
    for (int i=0;i<8;i++){
      int row = i*16 + srow;
      gload16(A  + (size_t)(m0+row)*K + kk + jsrc*8, &As[(i*256+tid)*8]);
      gload16(Bt + (size_t)(n0+row)*K + kk + jsrc*8, &Bs[(i*256+tid)*8]);
    }
    __syncthreads();
    #pragma unroll
    for (int ks=0; ks<4; ++ks){
      bf16x8 af[4], bfv[4];
      #pragma unroll
      for (int qq=0;qq<4;qq++){
        int row = wm + qq*16 + lm;
        int jj  = ks*4 + lk;
        af[qq] = *(const bf16x8*)&As[row*128 + ((jj^(row&15))<<3)];
      }
      #pragma unroll
      for (int qq=0;qq<4;qq++){
        int row = wn + qq*16 + lm;
        int jj  = ks*4 + lk;
        bfv[qq] = *(const bf16x8*)&Bs[row*128 + ((jj^(row&15))<<3)];
      }
      #pragma unroll
      for (int i=0;i<4;i++)
        #pragma unroll
        for (int j=0;j<4;j++)
          acc[i][j] = __builtin_amdgcn_mfma_f32_16x16x32_bf16(af[i], bfv[j], acc[i][j], 0,0,0);
    }
    __syncthreads();
  }
  #pragma unroll
  for (int i=0;i<4;i++){
    int mbase = m0 + wm + i*16 + lk*4;
    #pragma unroll
    for (int j=0;j<4;j++){
      int n = n0 + wn + j*16 + lm;
      #pragma unroll
      for (int r=0;r<4;r++){
        size_t idx = (size_t)(mbase+r)*N + n;
        float v = acc[i][j][r];
        if constexpr (EPI==2){ Cf[idx] = res[idx] + gate[n]*v; }
        else { Cf[idx] = res[idx] + gate[n]*(v + bias[n]); }
      }
    }
  }
}

// ---------------- GEMM 256Mx128N, 8 waves, per-wave 64x64 (fc1) ----------------
template<int EPI>
__global__ __launch_bounds__(512) void gemm256n_k(
    const hbf16* __restrict__ A1, const hbf16* __restrict__ B1,
    hbf16* __restrict__ Cb1, const float* __restrict__ bias1,
    const hbf16* __restrict__ A2, const hbf16* __restrict__ B2,
    hbf16* __restrict__ Cb2, const float* __restrict__ bias2,
    int nbx, int nby1, int nby2, int N, int K)
{
  __shared__ unsigned short As[256*64];   // 32 KB
  __shared__ unsigned short Bs[128*64];   // 16 KB
  const int tid = threadIdx.x;
  const int wv = tid>>6, ln = tid&63;
  const int nwg = nbx*(nby1+nby2), q = nwg>>3;
  const int w  = blockIdx.x;
  const int w2 = (w&7)*q + (w>>3);
  int n0, m0;
  const hbf16* A; const hbf16* Bt; hbf16* Cb; const float* bias;
  if (w2 < nbx*nby1){
    n0 = (w2/nby1)*128; m0 = (w2%nby1)*256;
    A=A1; Bt=B1; Cb=Cb1; bias=bias1;
  } else {
    int w3 = w2 - nbx*nby1;
    n0 = (w3/nby2)*128; m0 = (w3%nby2)*256;
    A=A2; Bt=B2; Cb=Cb2; bias=bias2;
  }
  const int wm = wv>>1, wn = wv&1;       // 4M x 2N waves
  const int lm = ln&15, lk = ln>>4;
  f32x4 acc[4][4];
  #pragma unroll
  for (int i=0;i<4;i++)
    #pragma unroll
    for (int j=0;j<4;j++) acc[i][j] = (f32x4){0.f,0.f,0.f,0.f};

  const int srow = tid>>3;               // 0..63
  const int jsrc = (tid&7) ^ (srow&7);
  const int NT = K>>6;

  for (int kt=0; kt<NT; ++kt){
    const int kk = kt<<6;
    #pragma unroll
    for (int i=0;i<4;i++)
      gload16(A + (size_t)(m0 + i*64 + srow)*K + kk + jsrc*8, &As[(i*512+tid)*8]);
    #pragma unroll
    for (int i=0;i<2;i++)
      gload16(Bt + (size_t)(n0 + i*64 + srow)*K + kk + jsrc*8, &Bs[(i*512+tid)*8]);
    __syncthreads();
    #pragma unroll
    for (int ks=0; ks<2; ++ks){
      bf16x8 af[4], bfv[4];
      #pragma unroll
      for (int qq=0;qq<4;qq++){
        int row = wm*64 + qq*16 + lm;
        int jj  = ks*4 + lk;
        af[qq] = *(const bf16x8*)&As[row*64 + ((jj^(row&7))<<3)];
      }
      #pragma unroll
      for (int qq=0;qq<4;qq++){
        int row = wn*64 + qq*16 + lm;
        int jj  = ks*4 + lk;
        bfv[qq] = *(const bf16x8*)&Bs[row*64 + ((jj^(row&7))<<3)];
      }
      #pragma unroll
      for (int i=0;i<4;i++)
        #pragma unroll
        for (int j=0;j<4;j++)
          acc[i][j] = __builtin_amdgcn_mfma_f32_16x16x32_bf16(af[i], bfv[j], acc[i][j], 0,0,0);
    }
    __syncthreads();
  }
  #pragma unroll
  for (int i=0;i<4;i++){
    int mbase = m0 + wm*64 + i*16 + lk*4;
    #pragma unroll
    for (int j=0;j<4;j++){
      int n = n0 + wn*64 + j*16 + lm;
      #pragma unroll
      for (int r=0;r<4;r++){
        size_t idx = (size_t)(mbase+r)*N + n;
        float v = acc[i][j][r];
        if constexpr (EPI==1){ Cb[idx] = __float2bfloat16(gelu_tanh(v + bias[n])); }
        else { Cb[idx] = __float2bfloat16(v); }
      }
    }
  }
}

// ---------------- qkv GEMM 256Mx128N with fused RMSNorm + RoPE epilogue ----------------
__global__ __launch_bounds__(512) void gemmqkv_k(
    const hbf16* __restrict__ A1, const hbf16* __restrict__ B1,
    const float* __restrict__ qn1, const float* __restrict__ kn1,
    int tok1, int rope1,
    const hbf16* __restrict__ A2, const hbf16* __restrict__ B2,
    const float* __restrict__ qn2, const float* __restrict__ kn2,
    int tok2, int rope2,
    const float* __restrict__ fcos_, const float* __restrict__ fsin_,
    hbf16* __restrict__ qb, hbf16* __restrict__ kb, hbf16* __restrict__ vb,
    int nbx, int nby1, int nby2, int K)
{
  __shared__ unsigned short As[256*64];
  __shared__ unsigned short Bs[128*64];
  __shared__ float ssb[2][256];
  const int tid = threadIdx.x;
  const int wv = tid>>6, ln = tid&63;
  const int nwg = nbx*(nby1+nby2), q = nwg>>3;
  const int w  = blockIdx.x;
  const int w2 = (w&7)*q + (w>>3);
  int n0, m0, tok, dorope;
  const hbf16* A; const hbf16* Bt; const float* qn; const float* kn;
  if (w2 < nbx*nby1){
    n0 = (w2/nby1)*128; m0 = (w2%nby1)*256;
    A=A1; Bt=B1; qn=qn1; kn=kn1; tok=tok1; dorope=rope1;
  } else {
    int w3 = w2 - nbx*nby1;
    n0 = (w3/nby2)*128; m0 = (w3%nby2)*256;
    A=A2; Bt=B2; qn=qn2; kn=kn2; tok=tok2; dorope=rope2;
  }
  const int wm = wv>>1, wn = wv&1;
  const int lm = ln&15, lk = ln>>4;
  f32x4 acc[4][4];
  #pragma unroll
  for (int i=0;i<4;i++)
    #pragma unroll
    for (int j=0;j<4;j++) acc[i][j] = (f32x4){0.f,0.f,0.f,0.f};

  const int srow = tid>>3;
  const int jsrc = (tid&7) ^ (srow&7);
  const int NT = K>>6;

  for (int kt=0; kt<NT; ++kt){
    const int kk = kt<<6;
    #pragma unroll
    for (int i=0;i<4;i++)
      gload16(A + (size_t)(m0 + i*64 + srow)*K + kk + jsrc*8, &As[(i*512+tid)*8]);
    #pragma unroll
    for (int i=0;i<2;i++)
      gload16(Bt + (size_t)(n0 + i*64 + srow)*K + kk + jsrc*8, &Bs[(i*512+tid)*8]);
    __syncthreads();
    #pragma unroll
    for (int ks=0; ks<2; ++ks){
      bf16x8 af[4], bfv[4];
      #pragma unroll
      for (int qq=0;qq<4;qq++){
        int row = wm*64 + qq*16 + lm;
        int jj  = ks*4 + lk;
        af[qq] = *(const bf16x8*)&As[row*64 + ((jj^(row&7))<<3)];
      }
      #pragma unroll
      for (int qq=0;qq<4;qq++){
        int row = wn*64 + qq*16 + lm;
        int jj  = ks*4 + lk;
        bfv[qq] = *(const bf16x8*)&Bs[row*64 + ((jj^(row&7))<<3)];
      }
      #pragma unroll
      for (int i=0;i<4;i++)
        #pragma unroll
        for (int j=0;j<4;j++)
          acc[i][j] = __builtin_amdgcn_mfma_f32_16x16x32_bf16(af[i], bfv[j], acc[i][j], 0,0,0);
    }
    __syncthreads();
  }

  const int which = n0 >> 11;        // 0:q 1:k 2:v
  const int head  = (n0 >> 7) & 15;
  if (which == 2){
    #pragma unroll
    for (int i=0;i<4;i++){
      int mbase = m0 + wm*64 + i*16 + lk*4;
      #pragma unroll
      for (int j=0;j<4;j++){
        int d = wn*64 + j*16 + lm;
        #pragma unroll
        for (int r=0;r<4;r++)
          vb[(size_t)(tok + mbase + r)*2048 + head*128 + d] = __float2bfloat16(acc[i][j][r]);
      }
    }
  } else {
    #pragma unroll
    for (int i=0;i<4;i++){
      #pragma unroll
      for (int r=0;r<4;r++){
        float p = 0.f;
        #pragma unroll
        for (int j=0;j<4;j++) p += acc[i][j][r]*acc[i][j][r];
        #pragma unroll
        for (int msk=1; msk<16; msk<<=1) p += __shfl_xor(p, msk, 64);
        if (lm == 0) ssb[wn][wm*64 + i*16 + lk*4 + r] = p;
      }
    }
    __syncthreads();
    const float* wgt = (which==0) ? qn : kn;
    const float qs = (which==0) ? 0.12751745f : 1.0f;   // 1/sqrt(128)*log2e for q
    hbf16* outb = (which==0) ? qb : kb;
    #pragma unroll
    for (int i=0;i<4;i++){
      #pragma unroll
      for (int r=0;r<4;r++){
        int row = wm*64 + i*16 + lk*4 + r;
        float ss = ssb[0][row] + ssb[1][row];
        float rs = rsqrtf(ss*(1.f/128.f) + 1e-6f) * qs;
        int t = m0 + row;
        #pragma unroll
        for (int j=0;j<4;j++){
          int d = wn*64 + j*16 + lm;
          float z = acc[i][j][r]*rs*wgt[d];
          float zp = __shfl_xor(z, 1, 64);
          float out;
          if (dorope){
            float c = fcos_[(size_t)t*128 + d];
            float s = fsin_[(size_t)t*128 + d];
            out = ((d&1)==0) ? (z*c - zp*s) : (z*c + zp*s);
          } else out = z;
          outb[(size_t)(tok + t)*2048 + head*128 + d] = __float2bfloat16(out);
        }
      }
    }
  }
}

// ---------------- flash attention: KV-split 4-way, bf16 partials ----------------
__global__ __launch_bounds__(512,4) void attn_k(
    const hbf16* __restrict__ Qg, const hbf16* __restrict__ Kg,
    const hbf16* __restrict__ Vtg, hbf16* __restrict__ sop01,
    hbf16* __restrict__ sop23, float* __restrict__ mlp)
{
  const int w = blockIdx.x;
  const int h = w & 15, quarter = (w>>4)&3, q0 = (w>>6)*128;
  const int tid = threadIdx.x, wv = tid>>6, ln = tid&63;
  __shared__ unsigned short Ks[2][64*128];
  __shared__ unsigned short Vs[2][128*64];
  __shared__ unsigned short Ps[8][16*64];

  bf16x8 qf[4];
  {
    const hbf16* qrow = Qg + (size_t)(q0 + wv*16 + (ln&15))*2048 + h*128 + (ln>>4)*8;
    #pragma unroll
    for (int ks=0;ks<4;ks++) qf[ks] = *(const bf16x8*)(qrow + ks*32);
  }

  f32x4 so[8];
  #pragma unroll
  for (int i=0;i<8;i++) so[i] = (f32x4){0.f,0.f,0.f,0.f};
  float m_run[4] = {-3e38f,-3e38f,-3e38f,-3e38f};
  float l_run[4] = {0.f,0.f,0.f,0.f};

  auto stage = [&](int buf, int kt){
    const int k0 = kt*64;
    #pragma unroll
    for (int i=0;i<2;i++){
      int c = i*512 + tid;
      int row = c>>4, jj = c&15;
      int js = jj ^ (row&7);
      gload16(Kg + (size_t)(k0+row)*2048 + h*128 + js*8, &Ks[buf][(i*512 + wv*64)*8]);
    }
    #pragma unroll
    for (int i=0;i<2;i++){
      int c = i*512 + tid;
      int row = c>>3, jj = c&7;
      int js = jj ^ (row&7);
      gload16(Vtg + (size_t)(h*128+row)*2304 + k0 + js*8, &Vs[buf][(i*512 + wv*64)*8]);
    }
  };

  const int t0 = quarter*9;
  stage(0, t0);
  __syncthreads();

  for (int it=0; it<9; ++it){
    const int cur = it&1;
    if (it+1 < 9) stage(cur^1, t0+it+1);

    f32x4 s[4];
    #pragma unroll
    for (int nb=0;nb<4;nb++) s[nb] = (f32x4){0.f,0.f,0.f,0.f};
    __builtin_amdgcn_s_setprio(1);
    #pragma unroll
    for (int ks=0;ks<4;ks++){
      #pragma unroll
      for (int nb=0;nb<4;nb++){
        int rk = nb*16 + (ln&15);
        int jq = ks*4 + (ln>>4);
        bf16x8 bk = *(const bf16x8*)&Ks[cur][rk*128 + ((jq^(rk&7))<<3)];
        s[nb] = __builtin_amdgcn_mfma_f32_16x16x32_bf16(qf[ks], bk, s[nb], 0,0,0);
      }
    }
    __builtin_amdgcn_s_setprio(0);

    float scl[4];
    #pragma unroll
    for (int r=0;r<4;r++){
      float m1 = fmaxf(fmaxf(s[0][r], s[1][r]), fmaxf(s[2][r], s[3][r]));
      #pragma unroll
      for (int msk=1; msk<16; msk<<=1) m1 = fmaxf(m1, __shfl_xor(m1, msk, 64));
      float mn = fmaxf(m_run[r], m1);
      scl[r] = exp2f(m_run[r] - mn);
      m_run[r] = mn;
    }
    #pragma unroll
    for (int nb=0;nb<4;nb++)
      #pragma unroll
      for (int r=0;r<4;r++)
        s[nb][r] = exp2f(s[nb][r] - m_run[r]);
    #pragma unroll
    for (int r=0;r<4;r++){
      float sm = s[0][r]+s[1][r]+s[2][r]+s[3][r];
      #pragma unroll
      for (int msk=1; msk<16; msk<<=1) sm += __shfl_xor(sm, msk, 64);
      l_run[r] = l_run[r]*scl[r] + sm;
    }
    #pragma unroll
    for (int nb2=0;nb2<8;nb2++)
      #pragma unroll
      for (int r=0;r<4;r++) so[nb2][r] *= scl[r];

    #pragma unroll
    for (int nb=0;nb<4;nb++)
      #pragma unroll
      for (int r=0;r<4;r++){
        int m = ((ln>>4)<<2) + r;
        int n = nb*16 + (ln&15);
        Ps[wv][m*64 + (((n>>3)^(m&7))<<3) + (n&7)] = f2bf_bits(s[nb][r]);
      }

    __builtin_amdgcn_s_setprio(1);
    #pragma unroll
    for (int ks=0;ks<2;ks++){
      int mrow = ln&15;
      bf16x8 pa = *(const bf16x8*)&Ps[wv][mrow*64 + (((ks*4+(ln>>4))^(mrow&7))<<3)];
      #pragma unroll
      for (int nb2=0;nb2<8;nb2++){
        int rv = nb2*16 + (ln&15);
        int jv = ks*4 + (ln>>4);
        bf16x8 bv = *(const bf16x8*)&Vs[cur][rv*64 + ((jv^(rv&7))<<3)];
        so[nb2] = __builtin_amdgcn_mfma_f32_16x16x32_bf16(pa, bv, so[nb2], 0,0,0);
      }
    }
    __builtin_amdgcn_s_setprio(0);
    __syncthreads();
  }

  hbf16* sbase = (quarter < 2 ? sop01 + (size_t)quarter*2304*2048
                              : sop23 + (size_t)(quarter-2)*2304*2048);
  #pragma unroll
  for (int r=0;r<4;r++){
    int m = q0 + wv*16 + ((ln>>4)<<2) + r;
    #pragma unroll
    for (int nb2=0;nb2<8;nb2++){
      int d = h*128 + nb2*16 + (ln&15);
      sbase[(size_t)m*2048 + d] = __float2bfloat16(so[nb2][r]);
    }
  }
  if ((ln&15)==0){
    #pragma unroll
    for (int r=0;r<4;r++){
      int m = q0 + wv*16 + ((ln>>4)<<2) + r;
      float* p = mlp + ((size_t)(quarter*2304 + m)*16 + h)*2;
      p[0] = m_run[r]; p[1] = l_run[r];
    }
  }
}

// merge the 4 KV quarters (bf16 partials)
__global__ __launch_bounds__(256) void amerge_k(const hbf16* __restrict__ sop01,
                                                const hbf16* __restrict__ sop23,
                                                const float* __restrict__ mlp,
                                                hbf16* __restrict__ Og){
  const int q = blockIdx.x, tid = threadIdx.x;
  const int d0 = tid*8, h = tid>>4;
  float mv[4], lv[4];
  float m = -3e38f;
  #pragma unroll
  for (int h4=0;h4<4;h4++){
    const float* p = mlp + ((size_t)(h4*2304 + q)*16 + h)*2;
    mv[h4] = p[0]; lv[h4] = p[1];
    m = fmaxf(m, mv[h4]);
  }
  float wgt[4], den = 0.f;
  #pragma unroll
  for (int h4=0;h4<4;h4++){ wgt[h4] = exp2f(mv[h4]-m); den += wgt[h4]*lv[h4]; }
  float inv = 1.0f/den;
  float acc[8] = {0,0,0,0,0,0,0,0};
  #pragma unroll
  for (int h4=0;h4<4;h4++){
    const hbf16* s = (h4<2 ? sop01 + (size_t)h4*2304*2048
                           : sop23 + (size_t)(h4-2)*2304*2048) + (size_t)q*2048 + d0;
    bf16x8 v = *(const bf16x8*)s;
    #pragma unroll
    for (int j=0;j<8;j++) acc[j] += wgt[h4]*(float)v[j];
  }
  hbf16* o = Og + (size_t)q*2048 + d0;
  #pragma unroll
  for (int j=0;j<8;j++) o[j] = __float2bfloat16(acc[j]*inv);
}

// ---------------- launcher ----------------

extern "C" void kernel_launch(void* const* d_in, const int* in_sizes, int n_in,
                              void* d_out, int out_size, void* d_ws, size_t ws_size,
                              hipStream_t stream) {
  (void)in_sizes; (void)n_in; (void)out_size; (void)ws_size;
  const float* img   = (const float*)d_in[0];
  const float* txt   = (const float*)d_in[1];
  const float* vec   = (const float*)d_in[2];
  const float* fcos  = (const float*)d_in[3];
  const float* fsin  = (const float*)d_in[4];
  const float* img_mod_w = (const float*)d_in[6];
  const float* img_mod_b = (const float*)d_in[7];
  const float* img_qkv_w = (const float*)d_in[8];
  const float* img_qn_w  = (const float*)d_in[9];
  const float* img_kn_w  = (const float*)d_in[10];
  const float* img_proj_w= (const float*)d_in[11];
  const float* img_fc1_w = (const float*)d_in[12];
  const float* img_fc1_b = (const float*)d_in[13];
  const float* img_fc2_w = (const float*)d_in[14];
  const float* img_fc2_b = (const float*)d_in[15];
  const float* txt_mod_w = (const float*)d_in[16];
  const float* txt_mod_b = (const float*)d_in[17];
  const float* txt_qkv_w = (const float*)d_in[18];
  const float* txt_qn_w  = (const float*)d_in[19];
  const float* txt_kn_w  = (const float*)d_in[20];
  const float* txt_proj_w= (const float*)d_in[21];
  const float* txt_fc1_w = (const float*)d_in[22];
  const float* txt_fc1_b = (const float*)d_in[23];
  const float* txt_fc2_w = (const float*)d_in[24];
  const float* txt_fc2_b = (const float*)d_in[25];

  float* out_img = (float*)d_out;
  float* out_txt = out_img + (size_t)2048*2048;

  char* ws = (char*)d_ws;
  size_t off = 0;
  auto alloc = [&](size_t bytes)->void*{
    void* p = ws + off; off += (bytes + 255) & ~(size_t)255; return p;
  };
  hbf16* wt1     = (hbf16*)alloc((size_t)16777216*2);
  hbf16* wt2     = (hbf16*)alloc((size_t)16777216*2);
  float* im      = (float*)alloc(12288*4);
  float* tm      = (float*)alloc(12288*4);
  float* part    = (float*)alloc((size_t)2*32*12288*4);
  // ix..tqkvb contiguous region later reused as sop01 (bf16 partials).
  hbf16* ix      = (hbf16*)alloc((size_t)2048*2048*2);
  hbf16* tx      = (hbf16*)alloc((size_t)256*2048*2);
  hbf16* iqkvb   = (hbf16*)alloc((size_t)2048*6144*2);   // pad region
  hbf16* tqkvb   = (hbf16*)alloc((size_t)256*6144*2);    // pad region
  hbf16* qb      = (hbf16*)alloc((size_t)2304*2048*2);
  hbf16* kb      = (hbf16*)alloc((size_t)2304*2048*2);
  hbf16* vb      = (hbf16*)alloc((size_t)2304*2048*2);
  hbf16* vtg     = (hbf16*)alloc((size_t)2048*2304*2);
  hbf16* attnb   = (hbf16*)alloc((size_t)2304*2048*2);
  float* img_mid = (float*)alloc((size_t)2048*2048*4);
  float* txt_mid = (float*)alloc((size_t)256*2048*4);
  hbf16* ix2     = (hbf16*)alloc((size_t)2048*2048*2);
  hbf16* tx2     = (hbf16*)alloc((size_t)256*2048*2);
  hbf16* h1i     = (hbf16*)alloc((size_t)2048*8192*2);
  hbf16* h1t     = (hbf16*)alloc((size_t)256*8192*2);
  float* mlp     = (float*)alloc((size_t)4*2304*16*2*4);
  (void)iqkvb; (void)tqkvb;
  hbf16* sop01 = (hbf16*)ix;
  hbf16* sop23 = (hbf16*)img_mid;

  // mod vectors (silu fused, img+txt in one dispatch pair)
  mod_part_k<<<dim3(12,32,2),256,0,stream>>>(vec, img_mod_w, txt_mod_w, part);
  mod_red_k<<<dim3(12,2),256,0,stream>>>(part, img_mod_b, txt_mod_b, im, tm);

  // pre-attn LN + modulate (fused img+txt)
  ln_mod_k<<<2304,256,0,stream>>>(img, txt, im+0, im+2048, tm+0, tm+2048, ix, tx);

  // qkv (fused img+txt), 256M tile, fused RMSNorm+RoPE epilogue -> qb/kb/vb
  transp3_k<<<dim3(96,16,2),256,0,stream>>>(img_qkv_w, wt1, txt_qkv_w, wt2, 2048, 6144);
  gemmqkv_k<<<432,512,0,stream>>>(ix, wt1, img_qn_w, img_kn_w, 0, 1,
                                  tx, wt2, txt_qn_w, txt_kn_w, 2048, 0,
                                  fcos, fsin, qb, kb, vb,
                                  48, 8, 1, 2048);

  // V transpose
  vtransp_k<<<dim3(36,32),256,0,stream>>>(vb, vtg);

  // attention (KV-split 4-way, bf16 partials) + merge
  attn_k<<<1152,512,0,stream>>>(qb, kb, vtg, sop01, sop23, mlp);
  amerge_k<<<2304,256,0,stream>>>(sop01, sop23, mlp, attnb);

  // proj + gate + residual (fused img+txt, BK=128)
  transp3_k<<<dim3(32,16,2),256,0,stream>>>(img_proj_w, wt1, txt_proj_w, wt2, 2048, 2048);
  gemmbk_k<2><<<288,256,0,stream>>>(attnb, wt1, img_mid, nullptr, im+4096, img,
                                    attnb + (size_t)2048*2048, wt2, txt_mid, nullptr, tm+4096, txt,
                                    16, 16, 2, 2048, 2048);

  // second LN + modulate (fused)
  ln_mod_k<<<2304,256,0,stream>>>(img_mid, txt_mid, im+6144, im+8192, tm+6144, tm+8192, ix2, tx2);

  // MLP fc1 (fused, 256M tile)
  transp3_k<<<dim3(128,16,2),256,0,stream>>>(img_fc1_w, wt1, txt_fc1_w, wt2, 2048, 8192);
  gemm256n_k<1><<<576,512,0,stream>>>(ix2, wt1, h1i, img_fc1_b,
                                      tx2, wt2, h1t, txt_fc1_b,
                                      64, 8, 1, 8192, 2048);

  // MLP fc2 (fused, BK=128)
  transp3_k<<<dim3(32,64,2),256,0,stream>>>(img_fc2_w, wt1, txt_fc2_w, wt2, 8192, 2048);
  gemmbk_k<3><<<288,256,0,stream>>>(h1i, wt1, out_img, img_fc2_b, im+10240, img_mid,
                                    h1t, wt2, out_txt, txt_fc2_b, tm+10240, txt_mid,
                                    16, 16, 2, 2048, 8192);
}

// Round 25
// 655.324 us; speedup vs baseline: 1.0350x; 1.0018x over previous
//
#include <hip/hip_runtime.h>
#include <hip/hip_bf16.h>
#include <cstdint>
#include <cstddef>

typedef __bf16 bf16x8 __attribute__((ext_vector_type(8)));
typedef float  f32x4  __attribute__((ext_vector_type(4)));
typedef __hip_bfloat16 hbf16;

#define DEVI static __device__ __forceinline__

DEVI unsigned short f2bf_bits(float x){
  hbf16 h = __float2bfloat16(x);
  return *reinterpret_cast<unsigned short*>(&h);
}
DEVI float gelu_tanh(float x){
  float u = x*(1.0f + 0.044715f*x*x);
  float t = exp2f(-2.3022119f*u);
  return x/(1.0f+t);
}

typedef __attribute__((address_space(1))) const unsigned int* gas_p;
typedef __attribute__((address_space(3))) unsigned int* las_p;
DEVI void gload16(const void* g, void* l){
  __builtin_amdgcn_global_load_lds((gas_p)g, (las_p)l, 16, 0, 0);
}

// ---------------- mod-vector GEMV (silu fused), dual-problem ----------------
__global__ __launch_bounds__(256) void mod_part_k(const float* __restrict__ vec_,
                                                  const float* __restrict__ W1,
                                                  const float* __restrict__ W2,
                                                  float* __restrict__ part){
  const float* W = blockIdx.z ? W2 : W1;
  float* po = part + (size_t)blockIdx.z*32*12288;
  int j  = blockIdx.x*1024 + threadIdx.x*4;
  int i0 = blockIdx.y*64;
  float4 acc = {0.f,0.f,0.f,0.f};
  for (int i=0;i<64;i++){
    float x = vec_[i0+i];
    float s = x/(1.0f+__expf(-x));        // silu fused
    float4 w = *(const float4*)(W + (size_t)(i0+i)*12288 + j);
    acc.x += s*w.x; acc.y += s*w.y; acc.z += s*w.z; acc.w += s*w.w;
  }
  *(float4*)(po + (size_t)blockIdx.y*12288 + j) = acc;
}

__global__ __launch_bounds__(256) void mod_red_k(const float* __restrict__ part,
                                                 const float* __restrict__ b1,
                                                 const float* __restrict__ b2,
                                                 float* __restrict__ out1,
                                                 float* __restrict__ out2){
  const float* p0 = part + (size_t)blockIdx.y*32*12288;
  const float* b  = blockIdx.y ? b2 : b1;
  float* out      = blockIdx.y ? out2 : out1;
  int j = blockIdx.x*1024 + threadIdx.x*4;
  float4 acc = *(const float4*)(b + j);
  #pragma unroll
  for (int y=0;y<32;y++){
    float4 p = *(const float4*)(p0 + (size_t)y*12288 + j);
    acc.x += p.x; acc.y += p.y; acc.z += p.z; acc.w += p.w;
  }
  *(float4*)(out + j) = acc;
}

// LayerNorm (no affine) + modulate -> bf16. Fused img + txt.
__global__ __launch_bounds__(256) void ln_mod_k(
    const float* __restrict__ Xi, const float* __restrict__ Xt,
    const float* __restrict__ sh_i, const float* __restrict__ sc_i,
    const float* __restrict__ sh_t, const float* __restrict__ sc_t,
    hbf16* __restrict__ Yi, hbf16* __restrict__ Yt){
  __shared__ float red[8];
  const int row = blockIdx.x, tid = threadIdx.x;
  const float* X; const float* sh; const float* sc; hbf16* Y; int r;
  if (row < 2048){ X = Xi; sh = sh_i; sc = sc_i; Y = Yi; r = row; }
  else           { X = Xt; sh = sh_t; sc = sc_t; Y = Yt; r = row - 2048; }
  const float* x = X + (size_t)r*2048;
  float4 a = *(const float4*)(x + tid*8);
  float4 c = *(const float4*)(x + tid*8 + 4);
  float s  = a.x+a.y+a.z+a.w + c.x+c.y+c.z+c.w;
  float s2 = a.x*a.x+a.y*a.y+a.z*a.z+a.w*a.w + c.x*c.x+c.y*c.y+c.z*c.z+c.w*c.w;
  #pragma unroll
  for (int m=1;m<64;m<<=1){ s += __shfl_xor(s,m,64); s2 += __shfl_xor(s2,m,64); }
  if ((tid&63)==0){ red[tid>>6] = s; red[4+(tid>>6)] = s2; }
  __syncthreads();
  float S  = red[0]+red[1]+red[2]+red[3];
  float S2 = red[4]+red[5]+red[6]+red[7];
  float mean = S*(1.f/2048.f);
  float var  = S2*(1.f/2048.f) - mean*mean;
  float rs = rsqrtf(var + 1e-6f);
  float xv[8] = {a.x,a.y,a.z,a.w,c.x,c.y,c.z,c.w};
  #pragma unroll
  for (int j=0;j<8;j++){
    int n = tid*8 + j;
    float yv = (xv[j]-mean)*rs*(1.f+sc[n]) + sh[n];
    Y[(size_t)r*2048 + n] = __float2bfloat16(yv);
  }
}

// transpose + fp32->bf16, fused img/txt pair: W [K][N] -> Wt [N][K].
__global__ __launch_bounds__(256) void transp3_k(const float* __restrict__ W1,
                                                 hbf16* __restrict__ Wt1,
                                                 const float* __restrict__ W2,
                                                 hbf16* __restrict__ Wt2,
                                                 int K, int N){
  const float* W = blockIdx.z ? W2 : W1;
  hbf16* Wt = blockIdx.z ? Wt2 : Wt1;
  __shared__ float tile[128][68];
  const int n0 = blockIdx.x*64, k0 = blockIdx.y*128;
  const int tid = threadIdx.x;
  #pragma unroll
  for (int i=0;i<8;i++){
    int c = i*256 + tid;
    int k = c>>4, nq = c&15;
    float4 v = *(const float4*)(W + (size_t)(k0+k)*N + n0 + nq*4);
    *(float4*)&tile[k][nq*4] = v;
  }
  __syncthreads();
  const int n = tid>>2, kseg = tid&3;
  unsigned short buf[32];
  #pragma unroll
  for (int j=0;j<32;j++) buf[j] = f2bf_bits(tile[kseg*32+j][n]);
  hbf16* dst = Wt + (size_t)(n0+n)*K + k0 + kseg*32;
  *(uint4*)(dst)      = *(const uint4*)&buf[0];
  *(uint4*)(dst + 8)  = *(const uint4*)&buf[8];
  *(uint4*)(dst + 16) = *(const uint4*)&buf[16];
  *(uint4*)(dst + 24) = *(const uint4*)&buf[24];
}

// bf16 transpose: V [2304][2048] -> Vt [2048][2304]
__global__ __launch_bounds__(256) void vtransp_k(const hbf16* __restrict__ V,
                                                 hbf16* __restrict__ Vt){
  __shared__ unsigned short tile[64][72];
  const int t0 = blockIdx.x*64, d0 = blockIdx.y*64;
  const int tid = threadIdx.x;
  #pragma unroll
  for (int i=0;i<2;i++){
    int c = i*256 + tid, row = c>>3, jj = c&7;
    uint4 v = *(const uint4*)(V + (size_t)(t0+row)*2048 + d0 + jj*8);
    *(uint4*)&tile[row][jj*8] = v;
  }
  __syncthreads();
  const int d = tid>>2, seg = tid&3;
  unsigned short buf[16];
  #pragma unroll
  for (int j=0;j<16;j++) buf[j] = tile[seg*16+j][d];
  *(uint4*)(Vt + (size_t)(d0+d)*2304 + t0 + seg*16)     = *(const uint4*)&buf[0];
  *(uint4*)(Vt + (size_t)(d0+d)*2304 + t0 + seg*16 + 8) = *(const uint4*)&buf[8];
}

// ---------------- GEMM 128^2, BK=128, dual-problem (proj / fc2) ----------------
// EPI: 2 fp32 res+gate*x, 3 fp32 res+gate*(x+bias).
template<int EPI>
__global__ __launch_bounds__(256,2) void gemmbk_k(
    const hbf16* __restrict__ A1, const hbf16* __restrict__ B1,
    float* __restrict__ Cf1, const float* __restrict__ bias1,
    const float* __restrict__ gate1, const float* __restrict__ res1,
    const hbf16* __restrict__ A2, const hbf16* __restrict__ B2,
    float* __restrict__ Cf2, const float* __restrict__ bias2,
    const float* __restrict__ gate2, const float* __restrict__ res2,
    int nbx, int nby1, int nby2, int N, int K)
{
  __shared__ unsigned short As[128*128];   // 32 KB
  __shared__ unsigned short Bs[128*128];   // 32 KB
  const int tid = threadIdx.x;
  const int wv = tid>>6, ln = tid&63;
  const int nwg = nbx*(nby1+nby2), q = nwg>>3;
  const int w  = blockIdx.x;
  const int w2 = (w&7)*q + (w>>3);
  int n0, m0;
  const hbf16* A; const hbf16* Bt; float* Cf;
  const float* bias; const float* gate; const float* res;
  if (w2 < nbx*nby1){
    n0 = (w2/nby1)*128; m0 = (w2%nby1)*128;
    A=A1; Bt=B1; Cf=Cf1; bias=bias1; gate=gate1; res=res1;
  } else {
    int w3 = w2 - nbx*nby1;
    n0 = (w3/nby2)*128; m0 = (w3%nby2)*128;
    A=A2; Bt=B2; Cf=Cf2; bias=bias2; gate=gate2; res=res2;
  }
  const int wm = (wv>>1)*64, wn = (wv&1)*64;
  const int lm = ln&15, lk = ln>>4;
  f32x4 acc[4][4];
  #pragma unroll
  for (int i=0;i<4;i++)
    #pragma unroll
    for (int j=0;j<4;j++) acc[i][j] = (f32x4){0.f,0.f,0.f,0.f};

  const int srow = tid>>4;                  // 0..15 (row mod 16)
  const int jsrc = (tid&15) ^ srow;         // involution partner of read swizzle
  const int NT = K>>7;

  for (int kt=0; kt<NT; ++kt){
    const int kk = kt<<7;
    #pragma unroll
    for (int i=0;i<8;i++){
      int row = i*16 + srow;
      gload16(A  + (size_t)(m0+row)*K + kk + jsrc*8, &As[(i*256+tid)*8]);
      gload16(Bt + (size_t)(n0+row)*K + kk + jsrc*8, &Bs[(i*256+tid)*8]);
    }
    __syncthreads();
    #pragma unroll
    for (int ks=0; ks<4; ++ks){
      bf16x8 af[4], bfv[4];
      #pragma unroll
      for (int qq=0;qq<4;qq++){
        int row = wm + qq*16 + lm;
        int jj  = ks*4 + lk;
        af[qq] = *(const bf16x8*)&As[row*128 + ((jj^(row&15))<<3)];
      }
      #pragma unroll
      for (int qq=0;qq<4;qq++){
        int row = wn + qq*16 + lm;
        int jj  = ks*4 + lk;
        bfv[qq] = *(const bf16x8*)&Bs[row*128 + ((jj^(row&15))<<3)];
      }
      #pragma unroll
      for (int i=0;i<4;i++)
        #pragma unroll
        for (int j=0;j<4;j++)
          acc[i][j] = __builtin_amdgcn_mfma_f32_16x16x32_bf16(af[i], bfv[j], acc[i][j], 0,0,0);
    }
    __syncthreads();
  }
  #pragma unroll
  for (int i=0;i<4;i++){
    int mbase = m0 + wm + i*16 + lk*4;
    #pragma unroll
    for (int j=0;j<4;j++){
      int n = n0 + wn + j*16 + lm;
      #pragma unroll
      for (int r=0;r<4;r++){
        size_t idx = (size_t)(mbase+r)*N + n;
        float v = acc[i][j][r];
        if constexpr (EPI==2){ Cf[idx] = res[idx] + gate[n]*v; }
        else { Cf[idx] = res[idx] + gate[n]*(v + bias[n]); }
      }
    }
  }
}

// ---------------- GEMM 256Mx128N, 8 waves, per-wave 64x64 (fc1) ----------------
template<int EPI>
__global__ __launch_bounds__(512) void gemm256n_k(
    const hbf16* __restrict__ A1, const hbf16* __restrict__ B1,
    hbf16* __restrict__ Cb1, const float* __restrict__ bias1,
    const hbf16* __restrict__ A2, const hbf16* __restrict__ B2,
    hbf16* __restrict__ Cb2, const float* __restrict__ bias2,
    int nbx, int nby1, int nby2, int N, int K)
{
  __shared__ unsigned short As[256*64];   // 32 KB
  __shared__ unsigned short Bs[128*64];   // 16 KB
  const int tid = threadIdx.x;
  const int wv = tid>>6, ln = tid&63;
  const int nwg = nbx*(nby1+nby2), q = nwg>>3;
  const int w  = blockIdx.x;
  const int w2 = (w&7)*q + (w>>3);
  int n0, m0;
  const hbf16* A; const hbf16* Bt; hbf16* Cb; const float* bias;
  if (w2 < nbx*nby1){
    n0 = (w2/nby1)*128; m0 = (w2%nby1)*256;
    A=A1; Bt=B1; Cb=Cb1; bias=bias1;
  } else {
    int w3 = w2 - nbx*nby1;
    n0 = (w3/nby2)*128; m0 = (w3%nby2)*256;
    A=A2; Bt=B2; Cb=Cb2; bias=bias2;
  }
  const int wm = wv>>1, wn = wv&1;       // 4M x 2N waves
  const int lm = ln&15, lk = ln>>4;
  f32x4 acc[4][4];
  #pragma unroll
  for (int i=0;i<4;i++)
    #pragma unroll
    for (int j=0;j<4;j++) acc[i][j] = (f32x4){0.f,0.f,0.f,0.f};

  const int srow = tid>>3;               // 0..63
  const int jsrc = (tid&7) ^ (srow&7);
  const int NT = K>>6;

  for (int kt=0; kt<NT; ++kt){
    const int kk = kt<<6;
    #pragma unroll
    for (int i=0;i<4;i++)
      gload16(A + (size_t)(m0 + i*64 + srow)*K + kk + jsrc*8, &As[(i*512+tid)*8]);
    #pragma unroll
    for (int i=0;i<2;i++)
      gload16(Bt + (size_t)(n0 + i*64 + srow)*K + kk + jsrc*8, &Bs[(i*512+tid)*8]);
    __syncthreads();
    #pragma unroll
    for (int ks=0; ks<2; ++ks){
      bf16x8 af[4], bfv[4];
      #pragma unroll
      for (int qq=0;qq<4;qq++){
        int row = wm*64 + qq*16 + lm;
        int jj  = ks*4 + lk;
        af[qq] = *(const bf16x8*)&As[row*64 + ((jj^(row&7))<<3)];
      }
      #pragma unroll
      for (int qq=0;qq<4;qq++){
        int row = wn*64 + qq*16 + lm;
        int jj  = ks*4 + lk;
        bfv[qq] = *(const bf16x8*)&Bs[row*64 + ((jj^(row&7))<<3)];
      }
      #pragma unroll
      for (int i=0;i<4;i++)
        #pragma unroll
        for (int j=0;j<4;j++)
          acc[i][j] = __builtin_amdgcn_mfma_f32_16x16x32_bf16(af[i], bfv[j], acc[i][j], 0,0,0);
    }
    __syncthreads();
  }
  #pragma unroll
  for (int i=0;i<4;i++){
    int mbase = m0 + wm*64 + i*16 + lk*4;
    #pragma unroll
    for (int j=0;j<4;j++){
      int n = n0 + wn*64 + j*16 + lm;
      #pragma unroll
      for (int r=0;r<4;r++){
        size_t idx = (size_t)(mbase+r)*N + n;
        float v = acc[i][j][r];
        if constexpr (EPI==1){ Cb[idx] = __float2bfloat16(gelu_tanh(v + bias[n])); }
        else { Cb[idx] = __float2bfloat16(v); }
      }
    }
  }
}

// ---------------- qkv GEMM 256Mx128N with fused RMSNorm + RoPE epilogue ----------------
__global__ __launch_bounds__(512) void gemmqkv_k(
    const hbf16* __restrict__ A1, const hbf16* __restrict__ B1,
    const float* __restrict__ qn1, const float* __restrict__ kn1,
    int tok1, int rope1,
    const hbf16* __restrict__ A2, const hbf16* __restrict__ B2,
    const float* __restrict__ qn2, const float* __restrict__ kn2,
    int tok2, int rope2,
    const float* __restrict__ fcos_, const float* __restrict__ fsin_,
    hbf16* __restrict__ qb, hbf16* __restrict__ kb, hbf16* __restrict__ vb,
    int nbx, int nby1, int nby2, int K)
{
  __shared__ unsigned short As[256*64];
  __shared__ unsigned short Bs[128*64];
  __shared__ float ssb[2][256];
  const int tid = threadIdx.x;
  const int wv = tid>>6, ln = tid&63;
  const int nwg = nbx*(nby1+nby2), q = nwg>>3;
  const int w  = blockIdx.x;
  const int w2 = (w&7)*q + (w>>3);
  int n0, m0, tok, dorope;
  const hbf16* A; const hbf16* Bt; const float* qn; const float* kn;
  if (w2 < nbx*nby1){
    n0 = (w2/nby1)*128; m0 = (w2%nby1)*256;
    A=A1; Bt=B1; qn=qn1; kn=kn1; tok=tok1; dorope=rope1;
  } else {
    int w3 = w2 - nbx*nby1;
    n0 = (w3/nby2)*128; m0 = (w3%nby2)*256;
    A=A2; Bt=B2; qn=qn2; kn=kn2; tok=tok2; dorope=rope2;
  }
  const int wm = wv>>1, wn = wv&1;
  const int lm = ln&15, lk = ln>>4;
  f32x4 acc[4][4];
  #pragma unroll
  for (int i=0;i<4;i++)
    #pragma unroll
    for (int j=0;j<4;j++) acc[i][j] = (f32x4){0.f,0.f,0.f,0.f};

  const int srow = tid>>3;
  const int jsrc = (tid&7) ^ (srow&7);
  const int NT = K>>6;

  for (int kt=0; kt<NT; ++kt){
    const int kk = kt<<6;
    #pragma unroll
    for (int i=0;i<4;i++)
      gload16(A + (size_t)(m0 + i*64 + srow)*K + kk + jsrc*8, &As[(i*512+tid)*8]);
    #pragma unroll
    for (int i=0;i<2;i++)
      gload16(Bt + (size_t)(n0 + i*64 + srow)*K + kk + jsrc*8, &Bs[(i*512+tid)*8]);
    __syncthreads();
    #pragma unroll
    for (int ks=0; ks<2; ++ks){
      bf16x8 af[4], bfv[4];
      #pragma unroll
      for (int qq=0;qq<4;qq++){
        int row = wm*64 + qq*16 + lm;
        int jj  = ks*4 + lk;
        af[qq] = *(const bf16x8*)&As[row*64 + ((jj^(row&7))<<3)];
      }
      #pragma unroll
      for (int qq=0;qq<4;qq++){
        int row = wn*64 + qq*16 + lm;
        int jj  = ks*4 + lk;
        bfv[qq] = *(const bf16x8*)&Bs[row*64 + ((jj^(row&7))<<3)];
      }
      #pragma unroll
      for (int i=0;i<4;i++)
        #pragma unroll
        for (int j=0;j<4;j++)
          acc[i][j] = __builtin_amdgcn_mfma_f32_16x16x32_bf16(af[i], bfv[j], acc[i][j], 0,0,0);
    }
    __syncthreads();
  }

  const int which = n0 >> 11;        // 0:q 1:k 2:v
  const int head  = (n0 >> 7) & 15;
  if (which == 2){
    #pragma unroll
    for (int i=0;i<4;i++){
      int mbase = m0 + wm*64 + i*16 + lk*4;
      #pragma unroll
      for (int j=0;j<4;j++){
        int d = wn*64 + j*16 + lm;
        #pragma unroll
        for (int r=0;r<4;r++)
          vb[(size_t)(tok + mbase + r)*2048 + head*128 + d] = __float2bfloat16(acc[i][j][r]);
      }
    }
  } else {
    #pragma unroll
    for (int i=0;i<4;i++){
      #pragma unroll
      for (int r=0;r<4;r++){
        float p = 0.f;
        #pragma unroll
        for (int j=0;j<4;j++) p += acc[i][j][r]*acc[i][j][r];
        #pragma unroll
        for (int msk=1; msk<16; msk<<=1) p += __shfl_xor(p, msk, 64);
        if (lm == 0) ssb[wn][wm*64 + i*16 + lk*4 + r] = p;
      }
    }
    __syncthreads();
    const float* wgt = (which==0) ? qn : kn;
    const float qs = (which==0) ? 0.12751745f : 1.0f;   // 1/sqrt(128)*log2e for q
    hbf16* outb = (which==0) ? qb : kb;
    #pragma unroll
    for (int i=0;i<4;i++){
      #pragma unroll
      for (int r=0;r<4;r++){
        int row = wm*64 + i*16 + lk*4 + r;
        float ss = ssb[0][row] + ssb[1][row];
        float rs = rsqrtf(ss*(1.f/128.f) + 1e-6f) * qs;
        int t = m0 + row;
        #pragma unroll
        for (int j=0;j<4;j++){
          int d = wn*64 + j*16 + lm;
          float z = acc[i][j][r]*rs*wgt[d];
          float zp = __shfl_xor(z, 1, 64);
          float out;
          if (dorope){
            float c = fcos_[(size_t)t*128 + d];
            float s = fsin_[(size_t)t*128 + d];
            out = ((d&1)==0) ? (z*c - zp*s) : (z*c + zp*s);
          } else out = z;
          outb[(size_t)(tok + t)*2048 + head*128 + d] = __float2bfloat16(out);
        }
      }
    }
  }
}

// ---------------- flash attention: KV-split 4-way, bf16 partials ----------------
__global__ __launch_bounds__(512,4) void attn_k(
    const hbf16* __restrict__ Qg, const hbf16* __restrict__ Kg,
    const hbf16* __restrict__ Vtg, hbf16* __restrict__ sop01,
    hbf16* __restrict__ sop23, float* __restrict__ mlp)
{
  const int w = blockIdx.x;
  const int h = w & 15, quarter = (w>>4)&3, q0 = (w>>6)*128;
  const int tid = threadIdx.x, wv = tid>>6, ln = tid&63;
  __shared__ unsigned short Ks[2][64*128];
  __shared__ unsigned short Vs[2][128*64];
  __shared__ unsigned short Ps[8][16*64];

  bf16x8 qf[4];
  {
    const hbf16* qrow = Qg + (size_t)(q0 + wv*16 + (ln&15))*2048 + h*128 + (ln>>4)*8;
    #pragma unroll
    for (int ks=0;ks<4;ks++) qf[ks] = *(const bf16x8*)(qrow + ks*32);
  }

  f32x4 so[8];
  #pragma unroll
  for (int i=0;i<8;i++) so[i] = (f32x4){0.f,0.f,0.f,0.f};
  float m_run[4] = {-3e38f,-3e38f,-3e38f,-3e38f};
  float l_run[4] = {0.f,0.f,0.f,0.f};

  auto stage = [&](int buf, int kt){
    const int k0 = kt*64;
    #pragma unroll
    for (int i=0;i<2;i++){
      int c = i*512 + tid;
      int row = c>>4, jj = c&15;
      int js = jj ^ (row&7);
      gload16(Kg + (size_t)(k0+row)*2048 + h*128 + js*8, &Ks[buf][(i*512 + wv*64)*8]);
    }
    #pragma unroll
    for (int i=0;i<2;i++){
      int c = i*512 + tid;
      int row = c>>3, jj = c&7;
      int js = jj ^ (row&7);
      gload16(Vtg + (size_t)(h*128+row)*2304 + k0 + js*8, &Vs[buf][(i*512 + wv*64)*8]);
    }
  };

  const int t0 = quarter*9;
  stage(0, t0);
  __syncthreads();

  for (int it=0; it<9; ++it){
    const int cur = it&1;
    if (it+1 < 9) stage(cur^1, t0+it+1);

    f32x4 s[4];
    #pragma unroll
    for (int nb=0;nb<4;nb++) s[nb] = (f32x4){0.f,0.f,0.f,0.f};
    __builtin_amdgcn_s_setprio(1);
    #pragma unroll
    for (int ks=0;ks<4;ks++){
      #pragma unroll
      for (int nb=0;nb<4;nb++){
        int rk = nb*16 + (ln&15);
        int jq = ks*4 + (ln>>4);
        bf16x8 bk = *(const bf16x8*)&Ks[cur][rk*128 + ((jq^(rk&7))<<3)];
        s[nb] = __builtin_amdgcn_mfma_f32_16x16x32_bf16(qf[ks], bk, s[nb], 0,0,0);
      }
    }
    __builtin_amdgcn_s_setprio(0);

    float scl[4];
    #pragma unroll
    for (int r=0;r<4;r++){
      float m1 = fmaxf(fmaxf(s[0][r], s[1][r]), fmaxf(s[2][r], s[3][r]));
      #pragma unroll
      for (int msk=1; msk<16; msk<<=1) m1 = fmaxf(m1, __shfl_xor(m1, msk, 64));
      float mn = fmaxf(m_run[r], m1);
      scl[r] = exp2f(m_run[r] - mn);
      m_run[r] = mn;
    }
    #pragma unroll
    for (int nb=0;nb<4;nb++)
      #pragma unroll
      for (int r=0;r<4;r++)
        s[nb][r] = exp2f(s[nb][r] - m_run[r]);
    #pragma unroll
    for (int r=0;r<4;r++){
      float sm = s[0][r]+s[1][r]+s[2][r]+s[3][r];
      #pragma unroll
      for (int msk=1; msk<16; msk<<=1) sm += __shfl_xor(sm, msk, 64);
      l_run[r] = l_run[r]*scl[r] + sm;
    }
    #pragma unroll
    for (int nb2=0;nb2<8;nb2++)
      #pragma unroll
      for (int r=0;r<4;r++) so[nb2][r] *= scl[r];

    #pragma unroll
    for (int nb=0;nb<4;nb++)
      #pragma unroll
      for (int r=0;r<4;r++){
        int m = ((ln>>4)<<2) + r;
        int n = nb*16 + (ln&15);
        Ps[wv][m*64 + (((n>>3)^(m&7))<<3) + (n&7)] = f2bf_bits(s[nb][r]);
      }

    __builtin_amdgcn_s_setprio(1);
    #pragma unroll
    for (int ks=0;ks<2;ks++){
      int mrow = ln&15;
      bf16x8 pa = *(const bf16x8*)&Ps[wv][mrow*64 + (((ks*4+(ln>>4))^(mrow&7))<<3)];
      #pragma unroll
      for (int nb2=0;nb2<8;nb2++){
        int rv = nb2*16 + (ln&15);
        int jv = ks*4 + (ln>>4);
        bf16x8 bv = *(const bf16x8*)&Vs[cur][rv*64 + ((jv^(rv&7))<<3)];
        so[nb2] = __builtin_amdgcn_mfma_f32_16x16x32_bf16(pa, bv, so[nb2], 0,0,0);
      }
    }
    __builtin_amdgcn_s_setprio(0);
    __syncthreads();
  }

  hbf16* sbase = (quarter < 2 ? sop01 + (size_t)quarter*2304*2048
                              : sop23 + (size_t)(quarter-2)*2304*2048);
  #pragma unroll
  for (int r=0;r<4;r++){
    int m = q0 + wv*16 + ((ln>>4)<<2) + r;
    #pragma unroll
    for (int nb2=0;nb2<8;nb2++){
      int d = h*128 + nb2*16 + (ln&15);
      sbase[(size_t)m*2048 + d] = __float2bfloat16(so[nb2][r]);
    }
  }
  if ((ln&15)==0){
    #pragma unroll
    for (int r=0;r<4;r++){
      int m = q0 + wv*16 + ((ln>>4)<<2) + r;
      float* p = mlp + ((size_t)(quarter*2304 + m)*16 + h)*2;
      p[0] = m_run[r]; p[1] = l_run[r];
    }
  }
}

// merge the 4 KV quarters (bf16 partials)
__global__ __launch_bounds__(256) void amerge_k(const hbf16* __restrict__ sop01,
                                                const hbf16* __restrict__ sop23,
                                                const float* __restrict__ mlp,
                                                hbf16* __restrict__ Og){
  const int q = blockIdx.x, tid = threadIdx.x;
  const int d0 = tid*8, h = tid>>4;
  float mv[4], lv[4];
  float m = -3e38f;
  #pragma unroll
  for (int h4=0;h4<4;h4++){
    const float* p = mlp + ((size_t)(h4*2304 + q)*16 + h)*2;
    mv[h4] = p[0]; lv[h4] = p[1];
    m = fmaxf(m, mv[h4]);
  }
  float wgt[4], den = 0.f;
  #pragma unroll
  for (int h4=0;h4<4;h4++){ wgt[h4] = exp2f(mv[h4]-m); den += wgt[h4]*lv[h4]; }
  float inv = 1.0f/den;
  float acc[8] = {0,0,0,0,0,0,0,0};
  #pragma unroll
  for (int h4=0;h4<4;h4++){
    const hbf16* s = (h4<2 ? sop01 + (size_t)h4*2304*2048
                           : sop23 + (size_t)(h4-2)*2304*2048) + (size_t)q*2048 + d0;
    bf16x8 v = *(const bf16x8*)s;
    #pragma unroll
    for (int j=0;j<8;j++) acc[j] += wgt[h4]*(float)v[j];
  }
  hbf16* o = Og + (size_t)q*2048 + d0;
  #pragma unroll
  for (int j=0;j<8;j++) o[j] = __float2bfloat16(acc[j]*inv);
}

// ---------------- launcher ----------------

extern "C" void kernel_launch(void* const* d_in, const int* in_sizes, int n_in,
                              void* d_out, int out_size, void* d_ws, size_t ws_size,
                              hipStream_t stream) {
  (void)in_sizes; (void)n_in; (void)out_size; (void)ws_size;
  const float* img   = (const float*)d_in[0];
  const float* txt   = (const float*)d_in[1];
  const float* vec   = (const float*)d_in[2];
  const float* fcos  = (const float*)d_in[3];
  const float* fsin  = (const float*)d_in[4];
  const float* img_mod_w = (const float*)d_in[6];
  const float* img_mod_b = (const float*)d_in[7];
  const float* img_qkv_w = (const float*)d_in[8];
  const float* img_qn_w  = (const float*)d_in[9];
  const float* img_kn_w  = (const float*)d_in[10];
  const float* img_proj_w= (const float*)d_in[11];
  const float* img_fc1_w = (const float*)d_in[12];
  const float* img_fc1_b = (const float*)d_in[13];
  const float* img_fc2_w = (const float*)d_in[14];
  const float* img_fc2_b = (const float*)d_in[15];
  const float* txt_mod_w = (const float*)d_in[16];
  const float* txt_mod_b = (const float*)d_in[17];
  const float* txt_qkv_w = (const float*)d_in[18];
  const float* txt_qn_w  = (const float*)d_in[19];
  const float* txt_kn_w  = (const float*)d_in[20];
  const float* txt_proj_w= (const float*)d_in[21];
  const float* txt_fc1_w = (const float*)d_in[22];
  const float* txt_fc1_b = (const float*)d_in[23];
  const float* txt_fc2_w = (const float*)d_in[24];
  const float* txt_fc2_b = (const float*)d_in[25];

  float* out_img = (float*)d_out;
  float* out_txt = out_img + (size_t)2048*2048;

  char* ws = (char*)d_ws;
  size_t off = 0;
  auto alloc = [&](size_t bytes)->void*{
    void* p = ws + off; off += (bytes + 255) & ~(size_t)255; return p;
  };
  hbf16* wt1     = (hbf16*)alloc((size_t)16777216*2);
  hbf16* wt2     = (hbf16*)alloc((size_t)16777216*2);
  float* im      = (float*)alloc(12288*4);
  float* tm      = (float*)alloc(12288*4);
  float* part    = (float*)alloc((size_t)2*32*12288*4);
  // ix..tqkvb contiguous region later reused as sop01 (bf16 partials).
  hbf16* ix      = (hbf16*)alloc((size_t)2048*2048*2);
  hbf16* tx      = (hbf16*)alloc((size_t)256*2048*2);
  hbf16* iqkvb   = (hbf16*)alloc((size_t)2048*6144*2);   // pad region
  hbf16* tqkvb   = (hbf16*)alloc((size_t)256*6144*2);    // pad region
  hbf16* qb      = (hbf16*)alloc((size_t)2304*2048*2);
  hbf16* kb      = (hbf16*)alloc((size_t)2304*2048*2);
  hbf16* vb      = (hbf16*)alloc((size_t)2304*2048*2);
  hbf16* vtg     = (hbf16*)alloc((size_t)2048*2304*2);
  hbf16* attnb   = (hbf16*)alloc((size_t)2304*2048*2);
  float* img_mid = (float*)alloc((size_t)2048*2048*4);
  float* txt_mid = (float*)alloc((size_t)256*2048*4);
  hbf16* ix2     = (hbf16*)alloc((size_t)2048*2048*2);
  hbf16* tx2     = (hbf16*)alloc((size_t)256*2048*2);
  hbf16* h1i     = (hbf16*)alloc((size_t)2048*8192*2);
  hbf16* h1t     = (hbf16*)alloc((size_t)256*8192*2);
  float* mlp     = (float*)alloc((size_t)4*2304*16*2*4);
  (void)iqkvb; (void)tqkvb;
  hbf16* sop01 = (hbf16*)ix;
  hbf16* sop23 = (hbf16*)img_mid;

  // mod vectors (silu fused, img+txt in one dispatch pair)
  mod_part_k<<<dim3(12,32,2),256,0,stream>>>(vec, img_mod_w, txt_mod_w, part);
  mod_red_k<<<dim3(12,2),256,0,stream>>>(part, img_mod_b, txt_mod_b, im, tm);

  // pre-attn LN + modulate (fused img+txt)
  ln_mod_k<<<2304,256,0,stream>>>(img, txt, im+0, im+2048, tm+0, tm+2048, ix, tx);

  // qkv (fused img+txt), 256M tile, fused RMSNorm+RoPE epilogue -> qb/kb/vb
  transp3_k<<<dim3(96,16,2),256,0,stream>>>(img_qkv_w, wt1, txt_qkv_w, wt2, 2048, 6144);
  gemmqkv_k<<<432,512,0,stream>>>(ix, wt1, img_qn_w, img_kn_w, 0, 1,
                                  tx, wt2, txt_qn_w, txt_kn_w, 2048, 0,
                                  fcos, fsin, qb, kb, vb,
                                  48, 8, 1, 2048);

  // V transpose
  vtransp_k<<<dim3(36,32),256,0,stream>>>(vb, vtg);

  // attention (KV-split 4-way, bf16 partials) + merge
  attn_k<<<1152,512,0,stream>>>(qb, kb, vtg, sop01, sop23, mlp);
  amerge_k<<<2304,256,0,stream>>>(sop01, sop23, mlp, attnb);

  // proj + gate + residual (fused img+txt, BK=128)
  transp3_k<<<dim3(32,16,2),256,0,stream>>>(img_proj_w, wt1, txt_proj_w, wt2, 2048, 2048);
  gemmbk_k<2><<<288,256,0,stream>>>(attnb, wt1, img_mid, nullptr, im+4096, img,
                                    attnb + (size_t)2048*2048, wt2, txt_mid, nullptr, tm+4096, txt,
                                    16, 16, 2, 2048, 2048);

  // second LN + modulate (fused)
  ln_mod_k<<<2304,256,0,stream>>>(img_mid, txt_mid, im+6144, im+8192, tm+6144, tm+8192, ix2, tx2);

  // MLP fc1 (fused, 256M tile)
  transp3_k<<<dim3(128,16,2),256,0,stream>>>(img_fc1_w, wt1, txt_fc1_w, wt2, 2048, 8192);
  gemm256n_k<1><<<576,512,0,stream>>>(ix2, wt1, h1i, img_fc1_b,
                                      tx2, wt2, h1t, txt_fc1_b,
                                      64, 8, 1, 8192, 2048);

  // MLP fc2 (fused, BK=128)
  transp3_k<<<dim3(32,64,2),256,0,stream>>>(img_fc2_w, wt1, txt_fc2_w, wt2, 8192, 2048);
  gemmbk_k<3><<<288,256,0,stream>>>(h1i, wt1, out_img, img_fc2_b, im+10240, img_mid,
                                    h1t, wt2, out_txt, txt_fc2_b, tm+10240, txt_mid,
                                    16, 16, 2, 2048, 8192);
}